// Round 27
// baseline (142.295 us; speedup 1.0000x reference)
//
#include <hip/hip_runtime.h>

#define HEADS 16
#define DH    64
#define NA    2048
#define NX    2048
#define NTOT  4096
#define DIMK  1024
#define NQKV  3072
#define SEG   256
#define NSEG  16

typedef float          f32x4  __attribute__((ext_vector_type(4)));
typedef short          bf16x8 __attribute__((ext_vector_type(8)));
typedef unsigned int   u32x4  __attribute__((ext_vector_type(4)));

// f32 -> bf16 bits, round-to-nearest-even (finite inputs)
__device__ __forceinline__ unsigned short f2bf(float f){
  unsigned int u = __builtin_bit_cast(unsigned int, f);
  unsigned int r = 0x7fffu + ((u >> 16) & 1u);
  return (unsigned short)((u + r) >> 16);
}
__device__ __forceinline__ float bf2f(unsigned short u){
  return __builtin_bit_cast(float, ((unsigned int)u) << 16);
}
__device__ __forceinline__ unsigned pack2(float a, float b){
  return (unsigned)f2bf(a) | ((unsigned)f2bf(b) << 16);
}

__global__ __launch_bounds__(256) void zero_kernel(float* __restrict__ out, int n){
  int i = blockIdx.x * 256 + threadIdx.x;
  if (i < n) out[i] = 0.f;
}

// ---------------- K0a: f32 -> bf16, both x and a in one dispatch ----------------
__global__ __launch_bounds__(256) void cvt_kernel(const float* __restrict__ x, const float* __restrict__ a,
                                                  unsigned short* __restrict__ Xb, unsigned short* __restrict__ Ab){
  int i = blockIdx.x * 256 + threadIdx.x;          // < 2097152
  const float* src = (i < 1048576) ? x : a;
  unsigned short* dst = (i < 1048576) ? Xb : Ab;
  const int j = i & 1048575;
  float4 v = ((const float4*)src)[j];
  ushort4 o;
  o.x = f2bf(v.x); o.y = f2bf(v.y); o.z = f2bf(v.z); o.w = f2bf(v.w);
  ((ushort4*)dst)[j] = o;
}

// ---------------- K0b: W [DIMK][NQKV] f32 -> WT [NQKV][DIMK] bf16 (both weights, grid.z) ----------------
__global__ __launch_bounds__(256) void wtr_kernel(const float* __restrict__ Wx, const float* __restrict__ Wa,
                                                  unsigned short* __restrict__ WTx, unsigned short* __restrict__ WTa){
  __shared__ float tile[32][33];
  const float* W = blockIdx.z ? Wa : Wx;
  unsigned short* WT = blockIdx.z ? WTa : WTx;
  int c0 = blockIdx.x * 32, k0 = blockIdx.y * 32;
  int tx = threadIdx.x, ty = threadIdx.y;
  #pragma unroll
  for (int i = 0; i < 32; i += 8) tile[ty+i][tx] = W[(size_t)(k0+ty+i)*NQKV + c0 + tx];
  __syncthreads();
  #pragma unroll
  for (int i = 0; i < 32; i += 8) WT[(size_t)(c0+ty+i)*DIMK + k0 + tx] = f2bf(tile[tx][ty+i]);
}

// ---------------- K0d: exact RoPE cos/sin table [n][fd][2], 131072 entries ----------------
__global__ __launch_bounds__(256) void rope_tab_kernel(float* __restrict__ tab){
  const int idx = blockIdx.x * 256 + threadIdx.x;   // < 131072
  const int n = idx >> 5, d = idx & 31;
  const float ang = (float)n * expf(-(float)d * 0.28782313662425572f);  // n * 10000^(-d/32)
  float sn, cs;
  sincosf(ang, &sn, &cs);
  float2 p; p.x = cs; p.y = sn;
  ((float2*)tab)[idx] = p;
}

// ---------------- K1: bf16 MFMA GEMM: BK=64, 2-phase dbuf gload_lds + XCD swizzle + fused epilogue ----------------
// 16 K-steps (half the barriers of BK=32); LDS 64KB -> 2 blocks/CU.
// LDS[r][c] holds global chunk c^(r&7) (8 16B-chunks/row); read slot (kb*4+lg)^(li&7).
__global__ __launch_bounds__(256,2) void gemm_qkv_kernel(
    const unsigned short* __restrict__ Xb, const unsigned short* __restrict__ Ab,
    const unsigned short* __restrict__ WTx, const unsigned short* __restrict__ WTa,
    unsigned short* __restrict__ qb, unsigned short* __restrict__ kb,
    unsigned short* __restrict__ vt,
    const float* __restrict__ gqx, const float* __restrict__ gkx,
    const float* __restrict__ gqa, const float* __restrict__ gka,
    const float* __restrict__ tab)
{
  __shared__ __align__(16) unsigned short As0[128*64];
  __shared__ __align__(16) unsigned short Bs0[128*64];
  __shared__ __align__(16) unsigned short As1[128*64];
  __shared__ __align__(16) unsigned short Bs1[128*64];

  const int bid = blockIdx.x;                       // 0..1535
  const int lid = (bid & 7) * 192 + (bid >> 3);     // bijective (1536 % 8 == 0)
  const int strm = lid / 768;                       // 0 = x, 1 = a
  const int rem  = lid - strm * 768;
  const int c0 = (rem >> 5) * 128;
  const int m0 = (rem & 31) * 128;

  const unsigned short* Xp = strm ? Ab  : Xb;
  const unsigned short* Wp = strm ? WTa : WTx;
  const float* gq = strm ? gqa : gqx;
  const float* gk = strm ? gka : gkx;
  const int n_off = strm ? 0 : NA;

  const int tid  = threadIdx.x;
  const int lane = tid & 63, w = tid >> 6;
  const int wr = w >> 1, wc = w & 1;
  const int li = lane & 15, lg = lane >> 4;

  // staging: one 1KB instruction covers 8 rows x 8 chunks; source chunk pre-swizzled
  const int sr8  = lane >> 3;                       // row within 8-row group
  const int sch  = lane & 7;                        // LDS chunk this lane fills
  const int sswz = sch ^ sr8;                       // global chunk to fetch (involution)
  const int rsw  = li & 7;                          // read-side row swizzle key (r&7 == li&7)

  f32x4 acc[4][4] = {};

  auto stage = [&](unsigned short* AsX, unsigned short* BsX, int kk){
    #pragma unroll
    for (int jj = 0; jj < 4; jj++){
      const int j = w*4 + jj;                       // 8-row group j: rows j*8 .. j*8+7
      const int r = j*8 + sr8;
      __builtin_amdgcn_global_load_lds(
        (const __attribute__((address_space(1))) unsigned int*)(Xp + (size_t)(m0+r)*DIMK + kk + sswz*8),
        (__attribute__((address_space(3))) unsigned int*)(AsX + j*512), 16, 0, 0);
      __builtin_amdgcn_global_load_lds(
        (const __attribute__((address_space(1))) unsigned int*)(Wp + (size_t)(c0+r)*DIMK + kk + sswz*8),
        (__attribute__((address_space(3))) unsigned int*)(BsX + j*512), 16, 0, 0);
    }
  };
  auto compute = [&](const unsigned short* AsX, const unsigned short* BsX){
    #pragma unroll
    for (int kb2 = 0; kb2 < 2; kb2++){
      bf16x8 af[4], bf[4];
      const int slot = ((kb2*4 + lg) ^ rsw) * 8;
      #pragma unroll
      for (int m = 0; m < 4; m++)
        af[m] = *(const bf16x8*)(&AsX[(wr*64 + m*16 + li)*64 + slot]);
      #pragma unroll
      for (int n = 0; n < 4; n++)
        bf[n] = *(const bf16x8*)(&BsX[(wc*64 + n*16 + li)*64 + slot]);
      #pragma unroll
      for (int m = 0; m < 4; m++)
        #pragma unroll
        for (int n = 0; n < 4; n++)
          acc[m][n] = __builtin_amdgcn_mfma_f32_16x16x32_bf16(af[m], bf[n], acc[m][n], 0, 0, 0);
    }
  };

  stage(As0, Bs0, 0);
  __syncthreads();
  for (int t = 0; t < 16; t += 2){
    stage(As1, Bs1, (t+1)*64);
    compute(As0, Bs0);
    __syncthreads();
    if (t + 2 < 16) stage(As0, Bs0, (t+2)*64);
    compute(As1, Bs1);
    __syncthreads();
  }

  const int colbase = c0 + wc*64;           // one head per wave
  const int which = colbase >> 10;          // 0=q, 1=k, 2=v (wave-uniform)
  const int h = (colbase >> 6) & 15;

  if (which < 2){
    const float* gv = (which == 0) ? gq : gk;
    unsigned short* dstb = (which == 0) ? qb : kb;
    float gl[4];
    #pragma unroll
    for (int n = 0; n < 4; n++) gl[n] = gv[h*64 + n*16 + li];
    #pragma unroll
    for (int m = 0; m < 4; m++){
      #pragma unroll
      for (int r = 0; r < 4; r++){
        float ss = acc[m][0][r]*acc[m][0][r] + acc[m][1][r]*acc[m][1][r]
                 + acc[m][2][r]*acc[m][2][r] + acc[m][3][r]*acc[m][3][r];
        ss += __shfl_xor(ss, 1, 64);
        ss += __shfl_xor(ss, 2, 64);
        ss += __shfl_xor(ss, 4, 64);
        ss += __shfl_xor(ss, 8, 64);
        const float sc = 8.0f / fmaxf(sqrtf(ss), 1e-12f);
        float v0 = acc[m][0][r]*sc*gl[0], v1 = acc[m][1][r]*sc*gl[1];
        float v2 = acc[m][2][r]*sc*gl[2], v3 = acc[m][3][r]*sc*gl[3];
        const int row = m0 + wr*64 + m*16 + lg*4 + r;
        const int bb = row >> 11, nn = row & 2047;
        const int n_g = nn + n_off;
        const float2 cs0 = ((const float2*)tab)[n_g*32 + li];        // fd = li
        const float2 cs1 = ((const float2*)tab)[n_g*32 + 16 + li];   // fd = 16+li
        const float o0 = v0*cs0.x - v2*cs0.y;   // d = li
        const float o1 = v1*cs1.x - v3*cs1.y;   // d = 16+li
        const float o2 = v2*cs0.x + v0*cs0.y;   // d = 32+li
        const float o3 = v3*cs1.x + v1*cs1.y;   // d = 48+li
        unsigned short* drow = dstb + ((size_t)(bb*HEADS + h)*NTOT + (size_t)n_g)*64;
        drow[li]      = f2bf(o0);
        drow[16 + li] = f2bf(o1);
        drow[32 + li] = f2bf(o2);
        drow[48 + li] = f2bf(o3);
      }
    }
  } else {
    #pragma unroll
    for (int m = 0; m < 4; m++){
      #pragma unroll
      for (int r = 0; r < 4; r++){
        const int row = m0 + wr*64 + m*16 + lg*4 + r;
        const int bb = row >> 11, nn = row & 2047;
        const int n_g = nn + n_off;
        unsigned short* vbase = vt + (size_t)(bb*HEADS + h)*DH*NTOT + n_g;
        #pragma unroll
        for (int n = 0; n < 4; n++)
          vbase[(size_t)(n*16 + li)*NTOT] = f2bf(acc[m][n][r]);
      }
    }
  }
}

// ---------------- K3: MFMA segG: G = skT (64x256) x v (256x64), zc = row-sum(skT) ----------------
__global__ __launch_bounds__(256,2) void segG_kernel(const unsigned short* __restrict__ kb,
                                                     const unsigned short* __restrict__ vt,
                                                     float* __restrict__ G, float* __restrict__ zc){
  __shared__ unsigned short skT[64*264];   // [d][l], stride 264
  __shared__ unsigned short Vts[64*264];   // [e][l], stride 264
  const int blk = blockIdx.x;              // bh*16 + s
  const int bh = blk >> 4, s = blk & 15;
  const int tid = threadIdx.x;
  const int w = tid >> 6, lane = tid & 63;
  const int li = lane & 15, lg = lane >> 4;
  const size_t segoffb = ((size_t)bh * NTOT + (size_t)s * SEG) * DH;

  #pragma unroll
  for (int it = 0; it < 8; it++){
    const int idx = tid + it*256;          // 2048 b128 chunks
    const int e = idx >> 5, jc = idx & 31;
    *(u32x4*)(Vts + e*264 + jc*8) =
      *(const u32x4*)(vt + (size_t)bh*DH*NTOT + (size_t)e*NTOT + s*SEG + jc*8);
  }
  // skT = elu(k)+1 transposed; k already bf16
  #pragma unroll
  for (int it = 0; it < 8; it++){
    const int idx = tid + it*256;          // 2048 chunks of 8 dims
    const int l = idx >> 3, dc = idx & 7;
    bf16x8 kk = *(const bf16x8*)(kb + segoffb + (size_t)l*64 + dc*8);
    #pragma unroll
    for (int t2 = 0; t2 < 8; t2++){
      const float xx = bf2f((unsigned short)kk[t2]);
      skT[(dc*8 + t2)*264 + l] = f2bf(xx > 0.f ? xx + 1.f : __expf(xx));
    }
  }
  __syncthreads();

  // zc: 4 threads per d-row
  {
    const int d = tid >> 2, q = tid & 3;
    float zz = 0.f;
    #pragma unroll
    for (int u = 0; u < 8; u++){
      bf16x8 vv = *(const bf16x8*)(skT + d*264 + q*64 + u*8);
      #pragma unroll
      for (int t2 = 0; t2 < 8; t2++)
        zz += bf2f((unsigned short)vv[t2]);
    }
    zz += __shfl_xor(zz, 1, 64);
    zz += __shfl_xor(zz, 2, 64);
    if (q == 0) zc[(size_t)blk*64 + d] = zz;
  }

  f32x4 acc[4] = {};
  #pragma unroll
  for (int k0 = 0; k0 < 256; k0 += 32){
    bf16x8 af = *(const bf16x8*)(skT + (w*16 + li)*264 + k0 + lg*8);
    #pragma unroll
    for (int n = 0; n < 4; n++){
      bf16x8 bf = *(const bf16x8*)(Vts + (n*16 + li)*264 + k0 + lg*8);
      acc[n] = __builtin_amdgcn_mfma_f32_16x16x32_bf16(af, bf, acc[n], 0, 0, 0);
    }
  }
  float* Gout = G + (size_t)blk * DH * DH;
  #pragma unroll
  for (int n = 0; n < 4; n++)
    #pragma unroll
    for (int r = 0; r < 4; r++)
      Gout[(w*16 + lg*4 + r)*64 + n*16 + li] = acc[n][r];
}

// ---------------- K4: exclusive prefix over segments -> Mp, zp (parallelized: grid 32x8) ----------------
__global__ __launch_bounds__(256) void prefix_kernel(const float* __restrict__ G,
                                                     const float* __restrict__ zc,
                                                     float* __restrict__ Mp, float* __restrict__ zp){
  const int bh = blockIdx.x, c = blockIdx.y, tid = threadIdx.x;
  const int e = c*512 + tid;          // this block handles elems [c*512, c*512+512)
  float run0 = 0.f, run1 = 0.f;
  for (int s = 0; s < NSEG; s++){
    const size_t base = ((size_t)bh * NSEG + s) * 4096;
    Mp[base + e]       = run0;  run0 += G[base + e];
    Mp[base + e + 256] = run1;  run1 += G[base + e + 256];
  }
  if (c == 0 && tid < DH){
    float rz = 0.f;
    for (int s = 0; s < NSEG; s++){
      zp[((size_t)bh*NSEG + s)*DH + tid] = rz;
      rz += zc[((size_t)bh*NSEG + s)*DH + tid];
    }
  }
}

// ---------------- K5: MFMA flash-attention per segment + gated memory readout ----------------
__global__ __launch_bounds__(256,1) void attn_mfma_kernel(
    const unsigned short* __restrict__ qb, const unsigned short* __restrict__ kb,
    const unsigned short* __restrict__ vt, const float* __restrict__ Mp,
    const float* __restrict__ zp, const float* __restrict__ beta,
    float* __restrict__ out)
{
  __shared__ unsigned short Qs[256*72];    // [row][d], stride 72 bf16
  __shared__ unsigned short KSs[256*72];   // K, later SQ*g/denm
  __shared__ unsigned short Vts[64*264];   // [e][j], stride 264
  __shared__ unsigned short Ps[4*64*72];   // per-wave P [i][j]
  __shared__ unsigned short Mts[64*72];    // M^T [e][d]
  __shared__ float den_s[256];
  __shared__ float zsh[64];

  const int blk = blockIdx.x;
  const int s = blk & 15, bh = blk >> 4;
  const int h = bh & 15, b = bh >> 4;
  const int tid = threadIdx.x;
  const int w = tid >> 6, lane = tid & 63;
  const int li = lane & 15, lg = lane >> 4;
  const size_t segoffb = ((size_t)bh * NTOT + (size_t)s * SEG) * DH;

  // Q/K staging: direct bf16 copies (rows are 128B contiguous)
  #pragma unroll
  for (int it = 0; it < 8; it++){
    const int idx = tid + it*256;            // 2048 chunks of 16B
    const int row = idx >> 3, jc = idx & 7;
    *(u32x4*)(Qs  + row*72 + jc*8) = *(const u32x4*)(qb + segoffb + (size_t)row*64 + jc*8);
    *(u32x4*)(KSs + row*72 + jc*8) = *(const u32x4*)(kb + segoffb + (size_t)row*64 + jc*8);
  }
  #pragma unroll
  for (int it = 0; it < 8; it++){
    const int idx = tid + it*256;            // 2048 b128 chunks
    const int e = idx >> 5, jc = idx & 31;
    *(u32x4*)(Vts + e*264 + jc*8) =
      *(const u32x4*)(vt + (size_t)bh*DH*NTOT + (size_t)e*NTOT + s*SEG + jc*8);
  }
  #pragma unroll
  for (int it = 0; it < 16; it++){
    const int idx = tid + it*256;            // 4096 elems of Mp [d][e]
    const int d = idx >> 6, e = idx & 63;
    Mts[e*72 + d] = f2bf(Mp[(size_t)blk*4096 + d*64 + e]);
  }
  if (tid < 64) zsh[tid] = zp[(size_t)blk*64 + tid];
  __syncthreads();

  f32x4 o_acc[4][4] = {};
  float denr[4] = {0.f, 0.f, 0.f, 0.f};
  const int qrow0 = w*64;
  bf16x8 qf[4][2];
  #pragma unroll
  for (int it = 0; it < 4; it++)
    #pragma unroll
    for (int kb2 = 0; kb2 < 2; kb2++)
      qf[it][kb2] = *(const bf16x8*)(Qs + (qrow0 + it*16 + li)*72 + kb2*32 + lg*8);

  for (int c = 0; c <= w; c++){
    f32x4 st[4][4] = {};
    #pragma unroll
    for (int jt = 0; jt < 4; jt++){
      bf16x8 kf0 = *(const bf16x8*)(KSs + (c*64 + jt*16 + li)*72 + 0  + lg*8);
      bf16x8 kf1 = *(const bf16x8*)(KSs + (c*64 + jt*16 + li)*72 + 32 + lg*8);
      #pragma unroll
      for (int it = 0; it < 4; it++){
        st[jt][it] = __builtin_amdgcn_mfma_f32_16x16x32_bf16(kf0, qf[it][0], st[jt][it], 0, 0, 0);
        st[jt][it] = __builtin_amdgcn_mfma_f32_16x16x32_bf16(kf1, qf[it][1], st[jt][it], 0, 0, 0);
      }
    }
    const bool diag = (c == w);
    #pragma unroll
    for (int jt = 0; jt < 4; jt++){
      #pragma unroll
      for (int it = 0; it < 4; it++){
        f32x4 p = st[jt][it];
        unsigned pb[4];
        #pragma unroll
        for (int r = 0; r < 4; r++){
          float pe = __expf(p[r] * 0.125f);
          if (diag && (jt*16 + lg*4 + r > it*16 + li)) pe = 0.f;
          pb[r] = __builtin_bit_cast(unsigned, pe) & 0xFFFF0000u;   // bf16 truncation
          p[r] = __builtin_bit_cast(float, pb[r]);                  // value actually used in PV
        }
        denr[it] += (p[0] + p[1]) + (p[2] + p[3]);
        uint2 pkk;
        pkk.x = (pb[0] >> 16) | pb[1];
        pkk.y = (pb[2] >> 16) | pb[3];
        *(uint2*)(Ps + w*4608 + (it*16 + li)*72 + jt*16 + lg*4) = pkk;
      }
    }
    bf16x8 pf[4][2];
    #pragma unroll
    for (int it = 0; it < 4; it++)
      #pragma unroll
      for (int kb2 = 0; kb2 < 2; kb2++)
        pf[it][kb2] = *(const bf16x8*)(Ps + w*4608 + (it*16 + li)*72 + kb2*32 + lg*8);
    #pragma unroll
    for (int et = 0; et < 4; et++){
      bf16x8 vf0 = *(const bf16x8*)(Vts + (et*16 + li)*264 + c*64 + 0  + lg*8);
      bf16x8 vf1 = *(const bf16x8*)(Vts + (et*16 + li)*264 + c*64 + 32 + lg*8);
      #pragma unroll
      for (int it = 0; it < 4; it++){
        o_acc[it][et] = __builtin_amdgcn_mfma_f32_16x16x32_bf16(pf[it][0], vf0, o_acc[it][et], 0, 0, 0);
        o_acc[it][et] = __builtin_amdgcn_mfma_f32_16x16x32_bf16(pf[it][1], vf1, o_acc[it][et], 0, 0, 0);
      }
    }
  }

  #pragma unroll
  for (int it = 0; it < 4; it++){
    denr[it] += __shfl_xor(denr[it], 16, 64);
    denr[it] += __shfl_xor(denr[it], 32, 64);
  }
  if (lane < 16){
    #pragma unroll
    for (int it = 0; it < 4; it++) den_s[qrow0 + it*16 + lane] = denr[it];
  }
  const float gate = 1.f / (1.f + __expf(-beta[h]));
  __syncthreads();

  {
    const int i = tid;
    float sqv[64];
    float denm = 0.f;
    #pragma unroll
    for (int u = 0; u < 8; u++){
      bf16x8 qv = *(const bf16x8*)(Qs + i*72 + u*8);
      #pragma unroll
      for (int t2 = 0; t2 < 8; t2++){
        float x = bf2f((unsigned short)qv[t2]);
        float sq = x > 0.f ? x + 1.f : __expf(x);
        sqv[u*8 + t2] = sq;
        denm += sq * zsh[u*8 + t2];
      }
    }
    const float c2 = gate / (denm + 1e-6f);
    #pragma unroll
    for (int u = 0; u < 16; u++){
      uint2 pw;
      pw.x = pack2(sqv[u*4]*c2,   sqv[u*4+1]*c2);
      pw.y = pack2(sqv[u*4+2]*c2, sqv[u*4+3]*c2);
      *(uint2*)(KSs + i*72 + u*4) = pw;
    }
  }
  __syncthreads();

  #pragma unroll
  for (int it = 0; it < 4; it++){
    #pragma unroll
    for (int r = 0; r < 4; r++){
      const float c1 = (1.f - gate) / den_s[qrow0 + it*16 + lg*4 + r];
      #pragma unroll
      for (int et = 0; et < 4; et++) o_acc[it][et][r] *= c1;
    }
  }
  #pragma unroll
  for (int kb2 = 0; kb2 < 2; kb2++){
    bf16x8 mf[4];
    #pragma unroll
    for (int et = 0; et < 4; et++)
      mf[et] = *(const bf16x8*)(Mts + (et*16 + li)*72 + kb2*32 + lg*8);
    #pragma unroll
    for (int it = 0; it < 4; it++){
      bf16x8 sf = *(const bf16x8*)(KSs + (qrow0 + it*16 + li)*72 + kb2*32 + lg*8);
      #pragma unroll
      for (int et = 0; et < 4; et++)
        o_acc[it][et] = __builtin_amdgcn_mfma_f32_16x16x32_bf16(sf, mf[et], o_acc[it][et], 0, 0, 0);
    }
  }

  #pragma unroll
  for (int it = 0; it < 4; it++){
    #pragma unroll
    for (int r = 0; r < 4; r++){
      const int n_g = s*SEG + qrow0 + it*16 + lg*4 + r;
      size_t o;
      if (n_g >= NA) o = ((size_t)b * NX + (size_t)(n_g - NA)) * 1024 + h * 64;
      else           o = 4194304u + ((size_t)b * NA + (size_t)n_g) * 1024 + h * 64;
      #pragma unroll
      for (int et = 0; et < 4; et++)
        out[o + et*16 + li] = o_acc[it][et][r];
    }
  }
}

extern "C" void kernel_launch(void* const* d_in, const int* in_sizes, int n_in,
                              void* d_out, int out_size, void* d_ws, size_t ws_size,
                              hipStream_t stream)
{
  (void)ws_size;
  const int expect[9] = {4194304, 4194304, 3145728, 3145728, 1024, 1024, 1024, 1024, 16};
  bool ok = (n_in == 9);
  if (ok) for (int i = 0; i < 9; i++) if (in_sizes[i] != expect[i]) { ok = false; break; }
  float* out = (float*)d_out;
  if (!ok){
    zero_kernel<<<dim3((out_size + 255)/256), dim3(256), 0, stream>>>(out, out_size);
    return;
  }

  const float* x    = (const float*)d_in[0];
  const float* a    = (const float*)d_in[1];
  const float* wx   = (const float*)d_in[2];
  const float* wa   = (const float*)d_in[3];
  const float* gqx  = (const float*)d_in[4];
  const float* gkx  = (const float*)d_in[5];
  const float* gqa  = (const float*)d_in[6];
  const float* gka  = (const float*)d_in[7];
  const float* beta = (const float*)d_in[8];

  // Workspace layout (~97.8 MB)
  char* wsb = (char*)d_ws;
  unsigned short* qb  = (unsigned short*)wsb;     // 16,777,216 B  [bh][n][d] bf16
  unsigned short* kb  = qb + 8388608;             // 16,777,216 B
  unsigned short* vtb = kb + 8388608;             // 16,777,216 B  [bh][d][n] bf16
  unsigned short* Xb  = vtb + 8388608;            //  8,388,608 B
  unsigned short* Ab  = Xb + 4194304;             //  8,388,608 B
  unsigned short* WTx = Ab + 4194304;             //  6,291,456 B
  unsigned short* WTa = WTx + 3145728;            //  6,291,456 B
  float* ropetab = (float*)(WTa + 3145728);       //  1,048,576 B
  float* G   = ropetab + 262144;                  //  8,388,608 B
  float* Mp  = G + 2097152;                       //  8,388,608 B
  float* zc  = Mp + 2097152;                      //    131,072 B
  float* zpb = zc + 32768;                        //    131,072 B

  cvt_kernel<<<dim3(8192), dim3(256), 0, stream>>>(x, a, Xb, Ab);
  wtr_kernel<<<dim3(96,32,2), dim3(32,8), 0, stream>>>(wx, wa, WTx, WTa);
  rope_tab_kernel<<<dim3(512), dim3(256), 0, stream>>>(ropetab);
  // a tokens occupy concatenated positions [0,2048); x tokens [2048,4096)
  gemm_qkv_kernel<<<dim3(1536), dim3(256), 0, stream>>>(Xb, Ab, WTx, WTa, qb, kb, vtb,
                                                        gqx, gkx, gqa, gka, ropetab);
  segG_kernel<<<dim3(512), dim3(256), 0, stream>>>(kb, vtb, G, zc);
  prefix_kernel<<<dim3(32,8), dim3(256), 0, stream>>>(G, zc, Mp, zpb);
  attn_mfma_kernel<<<dim3(512), dim3(256), 0, stream>>>(qb, kb, vtb, Mp, zpb, beta, out);
}

// Round 28
// 135.729 us; speedup vs baseline: 1.0484x; 1.0484x over previous
//
#include <hip/hip_runtime.h>

#define HEADS 16
#define DH    64
#define NA    2048
#define NX    2048
#define NTOT  4096
#define DIMK  1024
#define NQKV  3072
#define SEG   256
#define NSEG  16

typedef float          f32x4  __attribute__((ext_vector_type(4)));
typedef short          bf16x8 __attribute__((ext_vector_type(8)));
typedef unsigned int   u32x4  __attribute__((ext_vector_type(4)));

// f32 -> bf16 bits, round-to-nearest-even (finite inputs)
__device__ __forceinline__ unsigned short f2bf(float f){
  unsigned int u = __builtin_bit_cast(unsigned int, f);
  unsigned int r = 0x7fffu + ((u >> 16) & 1u);
  return (unsigned short)((u + r) >> 16);
}
__device__ __forceinline__ float bf2f(unsigned short u){
  return __builtin_bit_cast(float, ((unsigned int)u) << 16);
}
__device__ __forceinline__ unsigned pack2(float a, float b){
  return (unsigned)f2bf(a) | ((unsigned)f2bf(b) << 16);
}

__global__ __launch_bounds__(256) void zero_kernel(float* __restrict__ out, int n){
  int i = blockIdx.x * 256 + threadIdx.x;
  if (i < n) out[i] = 0.f;
}

// ---------------- K0: fused prep — cvt (x,a), wtr (wx,wa), rope table ----------------
// blocks [0,8192): cvt; [8192,14336): wtr; [14336,14848): rope table
__global__ __launch_bounds__(256) void prep_kernel(
    const float* __restrict__ x, const float* __restrict__ a,
    const float* __restrict__ Wx, const float* __restrict__ Wa,
    unsigned short* __restrict__ Xb, unsigned short* __restrict__ Ab,
    unsigned short* __restrict__ WTx, unsigned short* __restrict__ WTa,
    float* __restrict__ tab)
{
  __shared__ float tile[32][33];
  const int bid = blockIdx.x, tid = threadIdx.x;
  if (bid < 8192){
    const int i = bid * 256 + tid;                 // < 2097152
    const float* src = (i < 1048576) ? x : a;
    unsigned short* dst = (i < 1048576) ? Xb : Ab;
    const int j = i & 1048575;
    float4 v = ((const float4*)src)[j];
    ushort4 o;
    o.x = f2bf(v.x); o.y = f2bf(v.y); o.z = f2bf(v.z); o.w = f2bf(v.w);
    ((ushort4*)dst)[j] = o;
  } else if (bid < 14336){
    const int wid = bid - 8192;                    // < 6144
    const int z = wid / 3072, rem = wid - z*3072;
    const float* W = z ? Wa : Wx;
    unsigned short* WT = z ? WTa : WTx;
    const int c0 = (rem % 96) * 32, k0 = (rem / 96) * 32;
    const int tx = tid & 31, ty = tid >> 5;        // (32,8)
    #pragma unroll
    for (int i = 0; i < 32; i += 8) tile[ty+i][tx] = W[(size_t)(k0+ty+i)*NQKV + c0 + tx];
    __syncthreads();
    #pragma unroll
    for (int i = 0; i < 32; i += 8) WT[(size_t)(c0+ty+i)*DIMK + k0 + tx] = f2bf(tile[tx][ty+i]);
  } else {
    const int idx = (bid - 14336) * 256 + tid;     // < 131072
    const int n = idx >> 5, d = idx & 31;
    const float ang = (float)n * expf(-(float)d * 0.28782313662425572f);  // n * 10000^(-d/32)
    float sn, cs;
    sincosf(ang, &sn, &cs);
    float2 p; p.x = cs; p.y = sn;
    ((float2*)tab)[idx] = p;
  }
}

// ---------------- K1: bf16 MFMA GEMM: BK=64, 2-phase dbuf gload_lds + XCD swizzle + fused epilogue ----------------
__global__ __launch_bounds__(256,2) void gemm_qkv_kernel(
    const unsigned short* __restrict__ Xb, const unsigned short* __restrict__ Ab,
    const unsigned short* __restrict__ WTx, const unsigned short* __restrict__ WTa,
    unsigned short* __restrict__ qb, unsigned short* __restrict__ kb,
    unsigned short* __restrict__ vt,
    const float* __restrict__ gqx, const float* __restrict__ gkx,
    const float* __restrict__ gqa, const float* __restrict__ gka,
    const float* __restrict__ tab)
{
  __shared__ __align__(16) unsigned short As0[128*64];
  __shared__ __align__(16) unsigned short Bs0[128*64];
  __shared__ __align__(16) unsigned short As1[128*64];
  __shared__ __align__(16) unsigned short Bs1[128*64];

  const int bid = blockIdx.x;                       // 0..1535
  const int lid = (bid & 7) * 192 + (bid >> 3);     // bijective (1536 % 8 == 0)
  const int strm = lid / 768;                       // 0 = x, 1 = a
  const int rem  = lid - strm * 768;
  const int c0 = (rem >> 5) * 128;
  const int m0 = (rem & 31) * 128;

  const unsigned short* Xp = strm ? Ab  : Xb;
  const unsigned short* Wp = strm ? WTa : WTx;
  const float* gq = strm ? gqa : gqx;
  const float* gk = strm ? gka : gkx;
  const int n_off = strm ? 0 : NA;

  const int tid  = threadIdx.x;
  const int lane = tid & 63, w = tid >> 6;
  const int wr = w >> 1, wc = w & 1;
  const int li = lane & 15, lg = lane >> 4;

  const int sr8  = lane >> 3;
  const int sch  = lane & 7;
  const int sswz = sch ^ sr8;
  const int rsw  = li & 7;

  f32x4 acc[4][4] = {};

  auto stage = [&](unsigned short* AsX, unsigned short* BsX, int kk){
    #pragma unroll
    for (int jj = 0; jj < 4; jj++){
      const int j = w*4 + jj;
      const int r = j*8 + sr8;
      __builtin_amdgcn_global_load_lds(
        (const __attribute__((address_space(1))) unsigned int*)(Xp + (size_t)(m0+r)*DIMK + kk + sswz*8),
        (__attribute__((address_space(3))) unsigned int*)(AsX + j*512), 16, 0, 0);
      __builtin_amdgcn_global_load_lds(
        (const __attribute__((address_space(1))) unsigned int*)(Wp + (size_t)(c0+r)*DIMK + kk + sswz*8),
        (__attribute__((address_space(3))) unsigned int*)(BsX + j*512), 16, 0, 0);
    }
  };
  auto compute = [&](const unsigned short* AsX, const unsigned short* BsX){
    #pragma unroll
    for (int kb2 = 0; kb2 < 2; kb2++){
      bf16x8 af[4], bf[4];
      const int slot = ((kb2*4 + lg) ^ rsw) * 8;
      #pragma unroll
      for (int m = 0; m < 4; m++)
        af[m] = *(const bf16x8*)(&AsX[(wr*64 + m*16 + li)*64 + slot]);
      #pragma unroll
      for (int n = 0; n < 4; n++)
        bf[n] = *(const bf16x8*)(&BsX[(wc*64 + n*16 + li)*64 + slot]);
      #pragma unroll
      for (int m = 0; m < 4; m++)
        #pragma unroll
        for (int n = 0; n < 4; n++)
          acc[m][n] = __builtin_amdgcn_mfma_f32_16x16x32_bf16(af[m], bf[n], acc[m][n], 0, 0, 0);
    }
  };

  stage(As0, Bs0, 0);
  __syncthreads();
  for (int t = 0; t < 16; t += 2){
    stage(As1, Bs1, (t+1)*64);
    compute(As0, Bs0);
    __syncthreads();
    if (t + 2 < 16) stage(As0, Bs0, (t+2)*64);
    compute(As1, Bs1);
    __syncthreads();
  }

  const int colbase = c0 + wc*64;           // one head per wave
  const int which = colbase >> 10;          // 0=q, 1=k, 2=v (wave-uniform)
  const int h = (colbase >> 6) & 15;

  if (which < 2){
    const float* gv = (which == 0) ? gq : gk;
    unsigned short* dstb = (which == 0) ? qb : kb;
    float gl[4];
    #pragma unroll
    for (int n = 0; n < 4; n++) gl[n] = gv[h*64 + n*16 + li];
    #pragma unroll
    for (int m = 0; m < 4; m++){
      #pragma unroll
      for (int r = 0; r < 4; r++){
        float ss = acc[m][0][r]*acc[m][0][r] + acc[m][1][r]*acc[m][1][r]
                 + acc[m][2][r]*acc[m][2][r] + acc[m][3][r]*acc[m][3][r];
        ss += __shfl_xor(ss, 1, 64);
        ss += __shfl_xor(ss, 2, 64);
        ss += __shfl_xor(ss, 4, 64);
        ss += __shfl_xor(ss, 8, 64);
        const float sc = 8.0f / fmaxf(sqrtf(ss), 1e-12f);
        float v0 = acc[m][0][r]*sc*gl[0], v1 = acc[m][1][r]*sc*gl[1];
        float v2 = acc[m][2][r]*sc*gl[2], v3 = acc[m][3][r]*sc*gl[3];
        const int row = m0 + wr*64 + m*16 + lg*4 + r;
        const int bb = row >> 11, nn = row & 2047;
        const int n_g = nn + n_off;
        const float2 cs0 = ((const float2*)tab)[n_g*32 + li];        // fd = li
        const float2 cs1 = ((const float2*)tab)[n_g*32 + 16 + li];   // fd = 16+li
        const float o0 = v0*cs0.x - v2*cs0.y;   // d = li
        const float o1 = v1*cs1.x - v3*cs1.y;   // d = 16+li
        const float o2 = v2*cs0.x + v0*cs0.y;   // d = 32+li
        const float o3 = v3*cs1.x + v1*cs1.y;   // d = 48+li
        unsigned short* drow = dstb + ((size_t)(bb*HEADS + h)*NTOT + (size_t)n_g)*64;
        drow[li]      = f2bf(o0);
        drow[16 + li] = f2bf(o1);
        drow[32 + li] = f2bf(o2);
        drow[48 + li] = f2bf(o3);
      }
    }
  } else {
    #pragma unroll
    for (int m = 0; m < 4; m++){
      #pragma unroll
      for (int r = 0; r < 4; r++){
        const int row = m0 + wr*64 + m*16 + lg*4 + r;
        const int bb = row >> 11, nn = row & 2047;
        const int n_g = nn + n_off;
        unsigned short* vbase = vt + (size_t)(bb*HEADS + h)*DH*NTOT + n_g;
        #pragma unroll
        for (int n = 0; n < 4; n++)
          vbase[(size_t)(n*16 + li)*NTOT] = f2bf(acc[m][n][r]);
      }
    }
  }
}

// ---------------- K3: MFMA segG: G = skT (64x256) x v (256x64), zc = row-sum(skT) ----------------
__global__ __launch_bounds__(256,2) void segG_kernel(const unsigned short* __restrict__ kb,
                                                     const unsigned short* __restrict__ vt,
                                                     float* __restrict__ G, float* __restrict__ zc){
  __shared__ unsigned short skT[64*264];   // [d][l], stride 264
  __shared__ unsigned short Vts[64*264];   // [e][l], stride 264
  const int blk = blockIdx.x;              // bh*16 + s
  const int bh = blk >> 4, s = blk & 15;
  const int tid = threadIdx.x;
  const int w = tid >> 6, lane = tid & 63;
  const int li = lane & 15, lg = lane >> 4;
  const size_t segoffb = ((size_t)bh * NTOT + (size_t)s * SEG) * DH;

  #pragma unroll
  for (int it = 0; it < 8; it++){
    const int idx = tid + it*256;          // 2048 b128 chunks
    const int e = idx >> 5, jc = idx & 31;
    *(u32x4*)(Vts + e*264 + jc*8) =
      *(const u32x4*)(vt + (size_t)bh*DH*NTOT + (size_t)e*NTOT + s*SEG + jc*8);
  }
  // skT = elu(k)+1 transposed; k already bf16
  #pragma unroll
  for (int it = 0; it < 8; it++){
    const int idx = tid + it*256;          // 2048 chunks of 8 dims
    const int l = idx >> 3, dc = idx & 7;
    bf16x8 kk = *(const bf16x8*)(kb + segoffb + (size_t)l*64 + dc*8);
    #pragma unroll
    for (int t2 = 0; t2 < 8; t2++){
      const float xx = bf2f((unsigned short)kk[t2]);
      skT[(dc*8 + t2)*264 + l] = f2bf(xx > 0.f ? xx + 1.f : __expf(xx));
    }
  }
  __syncthreads();

  // zc: 4 threads per d-row
  {
    const int d = tid >> 2, q = tid & 3;
    float zz = 0.f;
    #pragma unroll
    for (int u = 0; u < 8; u++){
      bf16x8 vv = *(const bf16x8*)(skT + d*264 + q*64 + u*8);
      #pragma unroll
      for (int t2 = 0; t2 < 8; t2++)
        zz += bf2f((unsigned short)vv[t2]);
    }
    zz += __shfl_xor(zz, 1, 64);
    zz += __shfl_xor(zz, 2, 64);
    if (q == 0) zc[(size_t)blk*64 + d] = zz;
  }

  f32x4 acc[4] = {};
  #pragma unroll
  for (int k0 = 0; k0 < 256; k0 += 32){
    bf16x8 af = *(const bf16x8*)(skT + (w*16 + li)*264 + k0 + lg*8);
    #pragma unroll
    for (int n = 0; n < 4; n++){
      bf16x8 bf = *(const bf16x8*)(Vts + (n*16 + li)*264 + k0 + lg*8);
      acc[n] = __builtin_amdgcn_mfma_f32_16x16x32_bf16(af, bf, acc[n], 0, 0, 0);
    }
  }
  float* Gout = G + (size_t)blk * DH * DH;
  #pragma unroll
  for (int n = 0; n < 4; n++)
    #pragma unroll
    for (int r = 0; r < 4; r++)
      Gout[(w*16 + lg*4 + r)*64 + n*16 + li] = acc[n][r];
}

// ---------------- K4: exclusive prefix over segments -> Mp, zp (parallelized: grid 32x8) ----------------
__global__ __launch_bounds__(256) void prefix_kernel(const float* __restrict__ G,
                                                     const float* __restrict__ zc,
                                                     float* __restrict__ Mp, float* __restrict__ zp){
  const int bh = blockIdx.x, c = blockIdx.y, tid = threadIdx.x;
  const int e = c*512 + tid;          // this block handles elems [c*512, c*512+512)
  float run0 = 0.f, run1 = 0.f;
  for (int s = 0; s < NSEG; s++){
    const size_t base = ((size_t)bh * NSEG + s) * 4096;
    Mp[base + e]       = run0;  run0 += G[base + e];
    Mp[base + e + 256] = run1;  run1 += G[base + e + 256];
  }
  if (c == 0 && tid < DH){
    float rz = 0.f;
    for (int s = 0; s < NSEG; s++){
      zp[((size_t)bh*NSEG + s)*DH + tid] = rz;
      rz += zc[((size_t)bh*NSEG + s)*DH + tid];
    }
  }
}

// ---------------- K5: MFMA flash-attention; Q in registers, SQ in-register (no Qs/den_s LDS) ----------------
__global__ __launch_bounds__(256,1) void attn_mfma_kernel(
    const unsigned short* __restrict__ qb, const unsigned short* __restrict__ kb,
    const unsigned short* __restrict__ vt, const float* __restrict__ Mp,
    const float* __restrict__ zp, const float* __restrict__ beta,
    float* __restrict__ out)
{
  __shared__ unsigned short KSs[256*72];   // K [row][d], stride 72
  __shared__ unsigned short Vts[64*264];   // [e][j], stride 264
  __shared__ unsigned short Ps[4*64*72];   // per-wave P [i][j]
  __shared__ unsigned short Mts[64*72];    // M^T [e][d]
  __shared__ float zsh[64];

  const int blk = blockIdx.x;
  const int s = blk & 15, bh = blk >> 4;
  const int h = bh & 15, b = bh >> 4;
  const int tid = threadIdx.x;
  const int w = tid >> 6, lane = tid & 63;
  const int li = lane & 15, lg = lane >> 4;
  const size_t segoffb = ((size_t)bh * NTOT + (size_t)s * SEG) * DH;

  // K staging (rows are 128B contiguous)
  #pragma unroll
  for (int it = 0; it < 8; it++){
    const int idx = tid + it*256;            // 2048 chunks of 16B
    const int row = idx >> 3, jc = idx & 7;
    *(u32x4*)(KSs + row*72 + jc*8) = *(const u32x4*)(kb + segoffb + (size_t)row*64 + jc*8);
  }
  #pragma unroll
  for (int it = 0; it < 8; it++){
    const int idx = tid + it*256;            // 2048 b128 chunks
    const int e = idx >> 5, jc = idx & 31;
    *(u32x4*)(Vts + e*264 + jc*8) =
      *(const u32x4*)(vt + (size_t)bh*DH*NTOT + (size_t)e*NTOT + s*SEG + jc*8);
  }
  #pragma unroll
  for (int it = 0; it < 16; it++){
    const int idx = tid + it*256;            // 4096 elems of Mp [d][e]
    const int d = idx >> 6, e = idx & 63;
    Mts[e*72 + d] = f2bf(Mp[(size_t)blk*4096 + d*64 + e]);
  }
  if (tid < 64) zsh[tid] = zp[(size_t)blk*64 + tid];

  // Q fragments direct from global (wave's own 64 rows)
  const int qrow0 = w*64;
  bf16x8 qf[4][2];
  #pragma unroll
  for (int it = 0; it < 4; it++)
    #pragma unroll
    for (int kb2 = 0; kb2 < 2; kb2++)
      qf[it][kb2] = *(const bf16x8*)(qb + segoffb + (size_t)(qrow0 + it*16 + li)*64 + kb2*32 + lg*8);
  __syncthreads();

  f32x4 o_acc[4][4] = {};
  float denr[4] = {0.f, 0.f, 0.f, 0.f};

  for (int c = 0; c <= w; c++){
    f32x4 st[4][4] = {};
    #pragma unroll
    for (int jt = 0; jt < 4; jt++){
      bf16x8 kf0 = *(const bf16x8*)(KSs + (c*64 + jt*16 + li)*72 + 0  + lg*8);
      bf16x8 kf1 = *(const bf16x8*)(KSs + (c*64 + jt*16 + li)*72 + 32 + lg*8);
      #pragma unroll
      for (int it = 0; it < 4; it++){
        st[jt][it] = __builtin_amdgcn_mfma_f32_16x16x32_bf16(kf0, qf[it][0], st[jt][it], 0, 0, 0);
        st[jt][it] = __builtin_amdgcn_mfma_f32_16x16x32_bf16(kf1, qf[it][1], st[jt][it], 0, 0, 0);
      }
    }
    const bool diag = (c == w);
    #pragma unroll
    for (int jt = 0; jt < 4; jt++){
      #pragma unroll
      for (int it = 0; it < 4; it++){
        f32x4 p = st[jt][it];
        unsigned pb[4];
        #pragma unroll
        for (int r = 0; r < 4; r++){
          float pe = __expf(p[r] * 0.125f);
          if (diag && (jt*16 + lg*4 + r > it*16 + li)) pe = 0.f;
          pb[r] = __builtin_bit_cast(unsigned, pe) & 0xFFFF0000u;   // bf16 truncation
          p[r] = __builtin_bit_cast(float, pb[r]);                  // value actually used in PV
        }
        denr[it] += (p[0] + p[1]) + (p[2] + p[3]);
        uint2 pkk;
        pkk.x = (pb[0] >> 16) | pb[1];
        pkk.y = (pb[2] >> 16) | pb[3];
        *(uint2*)(Ps + w*4608 + (it*16 + li)*72 + jt*16 + lg*4) = pkk;
      }
    }
    bf16x8 pf[4][2];
    #pragma unroll
    for (int it = 0; it < 4; it++)
      #pragma unroll
      for (int kb2 = 0; kb2 < 2; kb2++)
        pf[it][kb2] = *(const bf16x8*)(Ps + w*4608 + (it*16 + li)*72 + kb2*32 + lg*8);
    #pragma unroll
    for (int et = 0; et < 4; et++){
      bf16x8 vf0 = *(const bf16x8*)(Vts + (et*16 + li)*264 + c*64 + 0  + lg*8);
      bf16x8 vf1 = *(const bf16x8*)(Vts + (et*16 + li)*264 + c*64 + 32 + lg*8);
      #pragma unroll
      for (int it = 0; it < 4; it++){
        o_acc[it][et] = __builtin_amdgcn_mfma_f32_16x16x32_bf16(pf[it][0], vf0, o_acc[it][et], 0, 0, 0);
        o_acc[it][et] = __builtin_amdgcn_mfma_f32_16x16x32_bf16(pf[it][1], vf1, o_acc[it][et], 0, 0, 0);
      }
    }
  }

  // softmax denominator: full reduction across lg groups (uniform in lg afterwards)
  #pragma unroll
  for (int it = 0; it < 4; it++){
    denr[it] += __shfl_xor(denr[it], 16, 64);
    denr[it] += __shfl_xor(denr[it], 32, 64);
  }
  const float gate = 1.f / (1.f + __expf(-beta[h]));

  // in-register SQ (A-frag layout) + per-row denm via shfl reduce
  bf16x8 sqf[4][2];
  #pragma unroll
  for (int it = 0; it < 4; it++){
    float sqv[16];
    float denm = 0.f;
    #pragma unroll
    for (int kb2 = 0; kb2 < 2; kb2++){
      #pragma unroll
      for (int t2 = 0; t2 < 8; t2++){
        const float xq = bf2f((unsigned short)qf[it][kb2][t2]);
        const float sq = xq > 0.f ? xq + 1.f : __expf(xq);
        sqv[kb2*8 + t2] = sq;
        denm += sq * zsh[kb2*32 + lg*8 + t2];
      }
    }
    denm += __shfl_xor(denm, 16, 64);
    denm += __shfl_xor(denm, 32, 64);
    const float c2 = gate / (denm + 1e-6f);
    #pragma unroll
    for (int kb2 = 0; kb2 < 2; kb2++){
      union { bf16x8 v; unsigned u[4]; } cc;
      #pragma unroll
      for (int p2 = 0; p2 < 4; p2++)
        cc.u[p2] = pack2(sqv[kb2*8 + 2*p2] * c2, sqv[kb2*8 + 2*p2 + 1] * c2);
      sqf[it][kb2] = cc.v;
    }
  }

  // scale local term by (1-gate)/den (den broadcast via shfl from lane lg*4+r)
  #pragma unroll
  for (int it = 0; it < 4; it++){
    #pragma unroll
    for (int r = 0; r < 4; r++){
      const float c1 = (1.f - gate) / __shfl(denr[it], lg*4 + r, 64);
      #pragma unroll
      for (int et = 0; et < 4; et++) o_acc[it][et][r] *= c1;
    }
  }
  // memory term MFMA with in-register sqf
  #pragma unroll
  for (int kb2 = 0; kb2 < 2; kb2++){
    bf16x8 mf[4];
    #pragma unroll
    for (int et = 0; et < 4; et++)
      mf[et] = *(const bf16x8*)(Mts + (et*16 + li)*72 + kb2*32 + lg*8);
    #pragma unroll
    for (int it = 0; it < 4; it++){
      #pragma unroll
      for (int et = 0; et < 4; et++)
        o_acc[it][et] = __builtin_amdgcn_mfma_f32_16x16x32_bf16(sqf[it][kb2], mf[et], o_acc[it][et], 0, 0, 0);
    }
  }

  #pragma unroll
  for (int it = 0; it < 4; it++){
    #pragma unroll
    for (int r = 0; r < 4; r++){
      const int n_g = s*SEG + qrow0 + it*16 + lg*4 + r;
      size_t o;
      if (n_g >= NA) o = ((size_t)b * NX + (size_t)(n_g - NA)) * 1024 + h * 64;
      else           o = 4194304u + ((size_t)b * NA + (size_t)n_g) * 1024 + h * 64;
      #pragma unroll
      for (int et = 0; et < 4; et++)
        out[o + et*16 + li] = o_acc[it][et][r];
    }
  }
}

extern "C" void kernel_launch(void* const* d_in, const int* in_sizes, int n_in,
                              void* d_out, int out_size, void* d_ws, size_t ws_size,
                              hipStream_t stream)
{
  (void)ws_size;
  const int expect[9] = {4194304, 4194304, 3145728, 3145728, 1024, 1024, 1024, 1024, 16};
  bool ok = (n_in == 9);
  if (ok) for (int i = 0; i < 9; i++) if (in_sizes[i] != expect[i]) { ok = false; break; }
  float* out = (float*)d_out;
  if (!ok){
    zero_kernel<<<dim3((out_size + 255)/256), dim3(256), 0, stream>>>(out, out_size);
    return;
  }

  const float* x    = (const float*)d_in[0];
  const float* a    = (const float*)d_in[1];
  const float* wx   = (const float*)d_in[2];
  const float* wa   = (const float*)d_in[3];
  const float* gqx  = (const float*)d_in[4];
  const float* gkx  = (const float*)d_in[5];
  const float* gqa  = (const float*)d_in[6];
  const float* gka  = (const float*)d_in[7];
  const float* beta = (const float*)d_in[8];

  // Workspace layout (~97.8 MB)
  char* wsb = (char*)d_ws;
  unsigned short* qb  = (unsigned short*)wsb;     // 16,777,216 B  [bh][n][d] bf16
  unsigned short* kb  = qb + 8388608;             // 16,777,216 B
  unsigned short* vtb = kb + 8388608;             // 16,777,216 B  [bh][d][n] bf16
  unsigned short* Xb  = vtb + 8388608;            //  8,388,608 B
  unsigned short* Ab  = Xb + 4194304;             //  8,388,608 B
  unsigned short* WTx = Ab + 4194304;             //  6,291,456 B
  unsigned short* WTa = WTx + 3145728;            //  6,291,456 B
  float* ropetab = (float*)(WTa + 3145728);       //  1,048,576 B
  float* G   = ropetab + 262144;                  //  8,388,608 B
  float* Mp  = G + 2097152;                       //  8,388,608 B
  float* zc  = Mp + 2097152;                      //    131,072 B
  float* zpb = zc + 32768;                        //    131,072 B

  prep_kernel<<<dim3(14848), dim3(256), 0, stream>>>(x, a, wx, wa, Xb, Ab, WTx, WTa, ropetab);
  // a tokens occupy concatenated positions [0,2048); x tokens [2048,4096)
  gemm_qkv_kernel<<<dim3(1536), dim3(256), 0, stream>>>(Xb, Ab, WTx, WTa, qb, kb, vtb,
                                                        gqx, gkx, gqa, gka, ropetab);
  segG_kernel<<<dim3(512), dim3(256), 0, stream>>>(kb, vtb, G, zc);
  prefix_kernel<<<dim3(32,8), dim3(256), 0, stream>>>(G, zc, Mp, zpb);
  attn_mfma_kernel<<<dim3(512), dim3(256), 0, stream>>>(qb, kb, vtb, Mp, zpb, beta, out);
}

// Round 29
// 132.756 us; speedup vs baseline: 1.0719x; 1.0224x over previous
//
#include <hip/hip_runtime.h>

#define HEADS 16
#define DH    64
#define NA    2048
#define NX    2048
#define NTOT  4096
#define DIMK  1024
#define NQKV  3072
#define SEG   256
#define NSEG  16

typedef float          f32x4  __attribute__((ext_vector_type(4)));
typedef short          bf16x8 __attribute__((ext_vector_type(8)));
typedef unsigned int   u32x4  __attribute__((ext_vector_type(4)));

// f32 -> bf16 bits, round-to-nearest-even (finite inputs)
__device__ __forceinline__ unsigned short f2bf(float f){
  unsigned int u = __builtin_bit_cast(unsigned int, f);
  unsigned int r = 0x7fffu + ((u >> 16) & 1u);
  return (unsigned short)((u + r) >> 16);
}
__device__ __forceinline__ float bf2f(unsigned short u){
  return __builtin_bit_cast(float, ((unsigned int)u) << 16);
}
__device__ __forceinline__ unsigned pack2(float a, float b){
  return (unsigned)f2bf(a) | ((unsigned)f2bf(b) << 16);
}

__global__ __launch_bounds__(256) void zero_kernel(float* __restrict__ out, int n){
  int i = blockIdx.x * 256 + threadIdx.x;
  if (i < n) out[i] = 0.f;
}

// ---------------- K0: fused prep — cvt (x,a), wtr (wx,wa), rope table ----------------
// blocks [0,8192): cvt; [8192,14336): wtr; [14336,14848): rope table
__global__ __launch_bounds__(256) void prep_kernel(
    const float* __restrict__ x, const float* __restrict__ a,
    const float* __restrict__ Wx, const float* __restrict__ Wa,
    unsigned short* __restrict__ Xb, unsigned short* __restrict__ Ab,
    unsigned short* __restrict__ WTx, unsigned short* __restrict__ WTa,
    float* __restrict__ tab)
{
  __shared__ float tile[32][33];
  const int bid = blockIdx.x, tid = threadIdx.x;
  if (bid < 8192){
    const int i = bid * 256 + tid;                 // < 2097152
    const float* src = (i < 1048576) ? x : a;
    unsigned short* dst = (i < 1048576) ? Xb : Ab;
    const int j = i & 1048575;
    float4 v = ((const float4*)src)[j];
    ushort4 o;
    o.x = f2bf(v.x); o.y = f2bf(v.y); o.z = f2bf(v.z); o.w = f2bf(v.w);
    ((ushort4*)dst)[j] = o;
  } else if (bid < 14336){
    const int wid = bid - 8192;                    // < 6144
    const int z = wid / 3072, rem = wid - z*3072;
    const float* W = z ? Wa : Wx;
    unsigned short* WT = z ? WTa : WTx;
    const int c0 = (rem % 96) * 32, k0 = (rem / 96) * 32;
    const int tx = tid & 31, ty = tid >> 5;        // (32,8)
    #pragma unroll
    for (int i = 0; i < 32; i += 8) tile[ty+i][tx] = W[(size_t)(k0+ty+i)*NQKV + c0 + tx];
    __syncthreads();
    #pragma unroll
    for (int i = 0; i < 32; i += 8) WT[(size_t)(c0+ty+i)*DIMK + k0 + tx] = f2bf(tile[tx][ty+i]);
  } else {
    const int idx = (bid - 14336) * 256 + tid;     // < 131072
    const int n = idx >> 5, d = idx & 31;
    const float ang = (float)n * expf(-(float)d * 0.28782313662425572f);  // n * 10000^(-d/32)
    float sn, cs;
    sincosf(ang, &sn, &cs);
    float2 p; p.x = cs; p.y = sn;
    ((float2*)tab)[idx] = p;
  }
}

// ---------------- K1: bf16 MFMA GEMM: BK=64, 2-phase dbuf gload_lds + XCD chunk + 8mx6c L2 supertile ----------------
__global__ __launch_bounds__(256,2) void gemm_qkv_kernel(
    const unsigned short* __restrict__ Xb, const unsigned short* __restrict__ Ab,
    const unsigned short* __restrict__ WTx, const unsigned short* __restrict__ WTa,
    unsigned short* __restrict__ qb, unsigned short* __restrict__ kb,
    unsigned short* __restrict__ vt,
    const float* __restrict__ gqx, const float* __restrict__ gkx,
    const float* __restrict__ gqa, const float* __restrict__ gka,
    const float* __restrict__ tab)
{
  __shared__ __align__(16) unsigned short As0[128*64];
  __shared__ __align__(16) unsigned short Bs0[128*64];
  __shared__ __align__(16) unsigned short As1[128*64];
  __shared__ __align__(16) unsigned short Bs1[128*64];

  // XCD chunking (bijective: 1536 % 8 == 0) + 8m x 6c supertiles within each 192-block chunk:
  // resident working set per XCD = 8 A-panels + 6 B-panels = 3.5 MB <= 4 MB L2.
  const int bid = blockIdx.x;                       // 0..1535
  const int lid = (bid & 7) * 192 + (bid >> 3);     // chunk-contiguous logical id
  const int strm = lid / 768;                       // 0 = x, 1 = a
  const int rem  = lid - strm * 768;
  const int cbase = (rem / 192) * 6;                // chunk's 6 c-panels
  const int idx   = rem % 192;
  const int st    = idx / 48;                       // 4 supertiles of 48 blocks
  const int si    = idx % 48;                       // 8m x 6c within supertile
  const int m0 = (st*8 + (si & 7)) * 128;
  const int c0 = (cbase + (si >> 3)) * 128;

  const unsigned short* Xp = strm ? Ab  : Xb;
  const unsigned short* Wp = strm ? WTa : WTx;
  const float* gq = strm ? gqa : gqx;
  const float* gk = strm ? gka : gkx;
  const int n_off = strm ? 0 : NA;

  const int tid  = threadIdx.x;
  const int lane = tid & 63, w = tid >> 6;
  const int wr = w >> 1, wc = w & 1;
  const int li = lane & 15, lg = lane >> 4;

  const int sr8  = lane >> 3;
  const int sch  = lane & 7;
  const int sswz = sch ^ sr8;
  const int rsw  = li & 7;

  f32x4 acc[4][4] = {};

  auto stage = [&](unsigned short* AsX, unsigned short* BsX, int kk){
    #pragma unroll
    for (int jj = 0; jj < 4; jj++){
      const int j = w*4 + jj;
      const int r = j*8 + sr8;
      __builtin_amdgcn_global_load_lds(
        (const __attribute__((address_space(1))) unsigned int*)(Xp + (size_t)(m0+r)*DIMK + kk + sswz*8),
        (__attribute__((address_space(3))) unsigned int*)(AsX + j*512), 16, 0, 0);
      __builtin_amdgcn_global_load_lds(
        (const __attribute__((address_space(1))) unsigned int*)(Wp + (size_t)(c0+r)*DIMK + kk + sswz*8),
        (__attribute__((address_space(3))) unsigned int*)(BsX + j*512), 16, 0, 0);
    }
  };
  auto compute = [&](const unsigned short* AsX, const unsigned short* BsX){
    #pragma unroll
    for (int kb2 = 0; kb2 < 2; kb2++){
      bf16x8 af[4], bf[4];
      const int slot = ((kb2*4 + lg) ^ rsw) * 8;
      #pragma unroll
      for (int m = 0; m < 4; m++)
        af[m] = *(const bf16x8*)(&AsX[(wr*64 + m*16 + li)*64 + slot]);
      #pragma unroll
      for (int n = 0; n < 4; n++)
        bf[n] = *(const bf16x8*)(&BsX[(wc*64 + n*16 + li)*64 + slot]);
      #pragma unroll
      for (int m = 0; m < 4; m++)
        #pragma unroll
        for (int n = 0; n < 4; n++)
          acc[m][n] = __builtin_amdgcn_mfma_f32_16x16x32_bf16(af[m], bf[n], acc[m][n], 0, 0, 0);
    }
  };

  stage(As0, Bs0, 0);
  __syncthreads();
  for (int t = 0; t < 16; t += 2){
    stage(As1, Bs1, (t+1)*64);
    compute(As0, Bs0);
    __syncthreads();
    if (t + 2 < 16) stage(As0, Bs0, (t+2)*64);
    compute(As1, Bs1);
    __syncthreads();
  }

  const int colbase = c0 + wc*64;           // one head per wave
  const int which = colbase >> 10;          // 0=q, 1=k, 2=v (wave-uniform)
  const int h = (colbase >> 6) & 15;

  if (which < 2){
    const float* gv = (which == 0) ? gq : gk;
    unsigned short* dstb = (which == 0) ? qb : kb;
    float gl[4];
    #pragma unroll
    for (int n = 0; n < 4; n++) gl[n] = gv[h*64 + n*16 + li];
    #pragma unroll
    for (int m = 0; m < 4; m++){
      #pragma unroll
      for (int r = 0; r < 4; r++){
        float ss = acc[m][0][r]*acc[m][0][r] + acc[m][1][r]*acc[m][1][r]
                 + acc[m][2][r]*acc[m][2][r] + acc[m][3][r]*acc[m][3][r];
        ss += __shfl_xor(ss, 1, 64);
        ss += __shfl_xor(ss, 2, 64);
        ss += __shfl_xor(ss, 4, 64);
        ss += __shfl_xor(ss, 8, 64);
        const float sc = 8.0f / fmaxf(sqrtf(ss), 1e-12f);
        float v0 = acc[m][0][r]*sc*gl[0], v1 = acc[m][1][r]*sc*gl[1];
        float v2 = acc[m][2][r]*sc*gl[2], v3 = acc[m][3][r]*sc*gl[3];
        const int row = m0 + wr*64 + m*16 + lg*4 + r;
        const int bb = row >> 11, nn = row & 2047;
        const int n_g = nn + n_off;
        const float2 cs0 = ((const float2*)tab)[n_g*32 + li];        // fd = li
        const float2 cs1 = ((const float2*)tab)[n_g*32 + 16 + li];   // fd = 16+li
        const float o0 = v0*cs0.x - v2*cs0.y;   // d = li
        const float o1 = v1*cs1.x - v3*cs1.y;   // d = 16+li
        const float o2 = v2*cs0.x + v0*cs0.y;   // d = 32+li
        const float o3 = v3*cs1.x + v1*cs1.y;   // d = 48+li
        unsigned short* drow = dstb + ((size_t)(bb*HEADS + h)*NTOT + (size_t)n_g)*64;
        drow[li]      = f2bf(o0);
        drow[16 + li] = f2bf(o1);
        drow[32 + li] = f2bf(o2);
        drow[48 + li] = f2bf(o3);
      }
    }
  } else {
    #pragma unroll
    for (int m = 0; m < 4; m++){
      #pragma unroll
      for (int r = 0; r < 4; r++){
        const int row = m0 + wr*64 + m*16 + lg*4 + r;
        const int bb = row >> 11, nn = row & 2047;
        const int n_g = nn + n_off;
        unsigned short* vbase = vt + (size_t)(bb*HEADS + h)*DH*NTOT + n_g;
        #pragma unroll
        for (int n = 0; n < 4; n++)
          vbase[(size_t)(n*16 + li)*NTOT] = f2bf(acc[m][n][r]);
      }
    }
  }
}

// ---------------- K3: MFMA segG: G = skT (64x256) x v (256x64), zc = row-sum(skT) ----------------
__global__ __launch_bounds__(256,2) void segG_kernel(const unsigned short* __restrict__ kb,
                                                     const unsigned short* __restrict__ vt,
                                                     float* __restrict__ G, float* __restrict__ zc){
  __shared__ unsigned short skT[64*264];   // [d][l], stride 264
  __shared__ unsigned short Vts[64*264];   // [e][l], stride 264
  const int blk = blockIdx.x;              // bh*16 + s
  const int bh = blk >> 4, s = blk & 15;
  const int tid = threadIdx.x;
  const int w = tid >> 6, lane = tid & 63;
  const int li = lane & 15, lg = lane >> 4;
  const size_t segoffb = ((size_t)bh * NTOT + (size_t)s * SEG) * DH;

  #pragma unroll
  for (int it = 0; it < 8; it++){
    const int idx = tid + it*256;          // 2048 b128 chunks
    const int e = idx >> 5, jc = idx & 31;
    *(u32x4*)(Vts + e*264 + jc*8) =
      *(const u32x4*)(vt + (size_t)bh*DH*NTOT + (size_t)e*NTOT + s*SEG + jc*8);
  }
  // skT = elu(k)+1 transposed; k already bf16
  #pragma unroll
  for (int it = 0; it < 8; it++){
    const int idx = tid + it*256;          // 2048 chunks of 8 dims
    const int l = idx >> 3, dc = idx & 7;
    bf16x8 kk = *(const bf16x8*)(kb + segoffb + (size_t)l*64 + dc*8);
    #pragma unroll
    for (int t2 = 0; t2 < 8; t2++){
      const float xx = bf2f((unsigned short)kk[t2]);
      skT[(dc*8 + t2)*264 + l] = f2bf(xx > 0.f ? xx + 1.f : __expf(xx));
    }
  }
  __syncthreads();

  // zc: 4 threads per d-row
  {
    const int d = tid >> 2, q = tid & 3;
    float zz = 0.f;
    #pragma unroll
    for (int u = 0; u < 8; u++){
      bf16x8 vv = *(const bf16x8*)(skT + d*264 + q*64 + u*8);
      #pragma unroll
      for (int t2 = 0; t2 < 8; t2++)
        zz += bf2f((unsigned short)vv[t2]);
    }
    zz += __shfl_xor(zz, 1, 64);
    zz += __shfl_xor(zz, 2, 64);
    if (q == 0) zc[(size_t)blk*64 + d] = zz;
  }

  f32x4 acc[4] = {};
  #pragma unroll
  for (int k0 = 0; k0 < 256; k0 += 32){
    bf16x8 af = *(const bf16x8*)(skT + (w*16 + li)*264 + k0 + lg*8);
    #pragma unroll
    for (int n = 0; n < 4; n++){
      bf16x8 bf = *(const bf16x8*)(Vts + (n*16 + li)*264 + k0 + lg*8);
      acc[n] = __builtin_amdgcn_mfma_f32_16x16x32_bf16(af, bf, acc[n], 0, 0, 0);
    }
  }
  float* Gout = G + (size_t)blk * DH * DH;
  #pragma unroll
  for (int n = 0; n < 4; n++)
    #pragma unroll
    for (int r = 0; r < 4; r++)
      Gout[(w*16 + lg*4 + r)*64 + n*16 + li] = acc[n][r];
}

// ---------------- K4: exclusive prefix over segments -> Mp, zp (parallelized: grid 32x8) ----------------
__global__ __launch_bounds__(256) void prefix_kernel(const float* __restrict__ G,
                                                     const float* __restrict__ zc,
                                                     float* __restrict__ Mp, float* __restrict__ zp){
  const int bh = blockIdx.x, c = blockIdx.y, tid = threadIdx.x;
  const int e = c*512 + tid;          // this block handles elems [c*512, c*512+512)
  float run0 = 0.f, run1 = 0.f;
  for (int s = 0; s < NSEG; s++){
    const size_t base = ((size_t)bh * NSEG + s) * 4096;
    Mp[base + e]       = run0;  run0 += G[base + e];
    Mp[base + e + 256] = run1;  run1 += G[base + e + 256];
  }
  if (c == 0 && tid < DH){
    float rz = 0.f;
    for (int s = 0; s < NSEG; s++){
      zp[((size_t)bh*NSEG + s)*DH + tid] = rz;
      rz += zc[((size_t)bh*NSEG + s)*DH + tid];
    }
  }
}

// ---------------- K5: MFMA flash-attention; Q in registers, SQ in-register (no Qs/den_s LDS) ----------------
__global__ __launch_bounds__(256,1) void attn_mfma_kernel(
    const unsigned short* __restrict__ qb, const unsigned short* __restrict__ kb,
    const unsigned short* __restrict__ vt, const float* __restrict__ Mp,
    const float* __restrict__ zp, const float* __restrict__ beta,
    float* __restrict__ out)
{
  __shared__ unsigned short KSs[256*72];   // K [row][d], stride 72
  __shared__ unsigned short Vts[64*264];   // [e][j], stride 264
  __shared__ unsigned short Ps[4*64*72];   // per-wave P [i][j]
  __shared__ unsigned short Mts[64*72];    // M^T [e][d]
  __shared__ float zsh[64];

  const int blk = blockIdx.x;
  const int s = blk & 15, bh = blk >> 4;
  const int h = bh & 15, b = bh >> 4;
  const int tid = threadIdx.x;
  const int w = tid >> 6, lane = tid & 63;
  const int li = lane & 15, lg = lane >> 4;
  const size_t segoffb = ((size_t)bh * NTOT + (size_t)s * SEG) * DH;

  // K staging (rows are 128B contiguous)
  #pragma unroll
  for (int it = 0; it < 8; it++){
    const int idx = tid + it*256;            // 2048 chunks of 16B
    const int row = idx >> 3, jc = idx & 7;
    *(u32x4*)(KSs + row*72 + jc*8) = *(const u32x4*)(kb + segoffb + (size_t)row*64 + jc*8);
  }
  #pragma unroll
  for (int it = 0; it < 8; it++){
    const int idx = tid + it*256;            // 2048 b128 chunks
    const int e = idx >> 5, jc = idx & 31;
    *(u32x4*)(Vts + e*264 + jc*8) =
      *(const u32x4*)(vt + (size_t)bh*DH*NTOT + (size_t)e*NTOT + s*SEG + jc*8);
  }
  #pragma unroll
  for (int it = 0; it < 16; it++){
    const int idx = tid + it*256;            // 4096 elems of Mp [d][e]
    const int d = idx >> 6, e = idx & 63;
    Mts[e*72 + d] = f2bf(Mp[(size_t)blk*4096 + d*64 + e]);
  }
  if (tid < 64) zsh[tid] = zp[(size_t)blk*64 + tid];

  // Q fragments direct from global (wave's own 64 rows)
  const int qrow0 = w*64;
  bf16x8 qf[4][2];
  #pragma unroll
  for (int it = 0; it < 4; it++)
    #pragma unroll
    for (int kb2 = 0; kb2 < 2; kb2++)
      qf[it][kb2] = *(const bf16x8*)(qb + segoffb + (size_t)(qrow0 + it*16 + li)*64 + kb2*32 + lg*8);
  __syncthreads();

  f32x4 o_acc[4][4] = {};
  float denr[4] = {0.f, 0.f, 0.f, 0.f};

  for (int c = 0; c <= w; c++){
    f32x4 st[4][4] = {};
    #pragma unroll
    for (int jt = 0; jt < 4; jt++){
      bf16x8 kf0 = *(const bf16x8*)(KSs + (c*64 + jt*16 + li)*72 + 0  + lg*8);
      bf16x8 kf1 = *(const bf16x8*)(KSs + (c*64 + jt*16 + li)*72 + 32 + lg*8);
      #pragma unroll
      for (int it = 0; it < 4; it++){
        st[jt][it] = __builtin_amdgcn_mfma_f32_16x16x32_bf16(kf0, qf[it][0], st[jt][it], 0, 0, 0);
        st[jt][it] = __builtin_amdgcn_mfma_f32_16x16x32_bf16(kf1, qf[it][1], st[jt][it], 0, 0, 0);
      }
    }
    const bool diag = (c == w);
    #pragma unroll
    for (int jt = 0; jt < 4; jt++){
      #pragma unroll
      for (int it = 0; it < 4; it++){
        f32x4 p = st[jt][it];
        unsigned pb[4];
        #pragma unroll
        for (int r = 0; r < 4; r++){
          float pe = __expf(p[r] * 0.125f);
          if (diag && (jt*16 + lg*4 + r > it*16 + li)) pe = 0.f;
          pb[r] = __builtin_bit_cast(unsigned, pe) & 0xFFFF0000u;   // bf16 truncation
          p[r] = __builtin_bit_cast(float, pb[r]);                  // value actually used in PV
        }
        denr[it] += (p[0] + p[1]) + (p[2] + p[3]);
        uint2 pkk;
        pkk.x = (pb[0] >> 16) | pb[1];
        pkk.y = (pb[2] >> 16) | pb[3];
        *(uint2*)(Ps + w*4608 + (it*16 + li)*72 + jt*16 + lg*4) = pkk;
      }
    }
    bf16x8 pf[4][2];
    #pragma unroll
    for (int it = 0; it < 4; it++)
      #pragma unroll
      for (int kb2 = 0; kb2 < 2; kb2++)
        pf[it][kb2] = *(const bf16x8*)(Ps + w*4608 + (it*16 + li)*72 + kb2*32 + lg*8);
    #pragma unroll
    for (int et = 0; et < 4; et++){
      bf16x8 vf0 = *(const bf16x8*)(Vts + (et*16 + li)*264 + c*64 + 0  + lg*8);
      bf16x8 vf1 = *(const bf16x8*)(Vts + (et*16 + li)*264 + c*64 + 32 + lg*8);
      #pragma unroll
      for (int it = 0; it < 4; it++){
        o_acc[it][et] = __builtin_amdgcn_mfma_f32_16x16x32_bf16(pf[it][0], vf0, o_acc[it][et], 0, 0, 0);
        o_acc[it][et] = __builtin_amdgcn_mfma_f32_16x16x32_bf16(pf[it][1], vf1, o_acc[it][et], 0, 0, 0);
      }
    }
  }

  // softmax denominator: full reduction across lg groups
  #pragma unroll
  for (int it = 0; it < 4; it++){
    denr[it] += __shfl_xor(denr[it], 16, 64);
    denr[it] += __shfl_xor(denr[it], 32, 64);
  }
  const float gate = 1.f / (1.f + __expf(-beta[h]));

  // in-register SQ (A-frag layout) + per-row denm via shfl reduce
  bf16x8 sqf[4][2];
  #pragma unroll
  for (int it = 0; it < 4; it++){
    float sqv[16];
    float denm = 0.f;
    #pragma unroll
    for (int kb2 = 0; kb2 < 2; kb2++){
      #pragma unroll
      for (int t2 = 0; t2 < 8; t2++){
        const float xq = bf2f((unsigned short)qf[it][kb2][t2]);
        const float sq = xq > 0.f ? xq + 1.f : __expf(xq);
        sqv[kb2*8 + t2] = sq;
        denm += sq * zsh[kb2*32 + lg*8 + t2];
      }
    }
    denm += __shfl_xor(denm, 16, 64);
    denm += __shfl_xor(denm, 32, 64);
    const float c2 = gate / (denm + 1e-6f);
    #pragma unroll
    for (int kb2 = 0; kb2 < 2; kb2++){
      union { bf16x8 v; unsigned u[4]; } cc;
      #pragma unroll
      for (int p2 = 0; p2 < 4; p2++)
        cc.u[p2] = pack2(sqv[kb2*8 + 2*p2] * c2, sqv[kb2*8 + 2*p2 + 1] * c2);
      sqf[it][kb2] = cc.v;
    }
  }

  // scale local term by (1-gate)/den (den broadcast via shfl from lane lg*4+r)
  #pragma unroll
  for (int it = 0; it < 4; it++){
    #pragma unroll
    for (int r = 0; r < 4; r++){
      const float c1 = (1.f - gate) / __shfl(denr[it], lg*4 + r, 64);
      #pragma unroll
      for (int et = 0; et < 4; et++) o_acc[it][et][r] *= c1;
    }
  }
  // memory term MFMA with in-register sqf
  #pragma unroll
  for (int kb2 = 0; kb2 < 2; kb2++){
    bf16x8 mf[4];
    #pragma unroll
    for (int et = 0; et < 4; et++)
      mf[et] = *(const bf16x8*)(Mts + (et*16 + li)*72 + kb2*32 + lg*8);
    #pragma unroll
    for (int it = 0; it < 4; it++){
      #pragma unroll
      for (int et = 0; et < 4; et++)
        o_acc[it][et] = __builtin_amdgcn_mfma_f32_16x16x32_bf16(sqf[it][kb2], mf[et], o_acc[it][et], 0, 0, 0);
    }
  }

  #pragma unroll
  for (int it = 0; it < 4; it++){
    #pragma unroll
    for (int r = 0; r < 4; r++){
      const int n_g = s*SEG + qrow0 + it*16 + lg*4 + r;
      size_t o;
      if (n_g >= NA) o = ((size_t)b * NX + (size_t)(n_g - NA)) * 1024 + h * 64;
      else           o = 4194304u + ((size_t)b * NA + (size_t)n_g) * 1024 + h * 64;
      #pragma unroll
      for (int et = 0; et < 4; et++)
        out[o + et*16 + li] = o_acc[it][et][r];
    }
  }
}

extern "C" void kernel_launch(void* const* d_in, const int* in_sizes, int n_in,
                              void* d_out, int out_size, void* d_ws, size_t ws_size,
                              hipStream_t stream)
{
  (void)ws_size;
  const int expect[9] = {4194304, 4194304, 3145728, 3145728, 1024, 1024, 1024, 1024, 16};
  bool ok = (n_in == 9);
  if (ok) for (int i = 0; i < 9; i++) if (in_sizes[i] != expect[i]) { ok = false; break; }
  float* out = (float*)d_out;
  if (!ok){
    zero_kernel<<<dim3((out_size + 255)/256), dim3(256), 0, stream>>>(out, out_size);
    return;
  }

  const float* x    = (const float*)d_in[0];
  const float* a    = (const float*)d_in[1];
  const float* wx   = (const float*)d_in[2];
  const float* wa   = (const float*)d_in[3];
  const float* gqx  = (const float*)d_in[4];
  const float* gkx  = (const float*)d_in[5];
  const float* gqa  = (const float*)d_in[6];
  const float* gka  = (const float*)d_in[7];
  const float* beta = (const float*)d_in[8];

  // Workspace layout (~97.8 MB)
  char* wsb = (char*)d_ws;
  unsigned short* qb  = (unsigned short*)wsb;     // 16,777,216 B  [bh][n][d] bf16
  unsigned short* kb  = qb + 8388608;             // 16,777,216 B
  unsigned short* vtb = kb + 8388608;             // 16,777,216 B  [bh][d][n] bf16
  unsigned short* Xb  = vtb + 8388608;            //  8,388,608 B
  unsigned short* Ab  = Xb + 4194304;             //  8,388,608 B
  unsigned short* WTx = Ab + 4194304;             //  6,291,456 B
  unsigned short* WTa = WTx + 3145728;            //  6,291,456 B
  float* ropetab = (float*)(WTa + 3145728);       //  1,048,576 B
  float* G   = ropetab + 262144;                  //  8,388,608 B
  float* Mp  = G + 2097152;                       //  8,388,608 B
  float* zc  = Mp + 2097152;                      //    131,072 B
  float* zpb = zc + 32768;                        //    131,072 B

  prep_kernel<<<dim3(14848), dim3(256), 0, stream>>>(x, a, wx, wa, Xb, Ab, WTx, WTa, ropetab);
  // a tokens occupy concatenated positions [0,2048); x tokens [2048,4096)
  gemm_qkv_kernel<<<dim3(1536), dim3(256), 0, stream>>>(Xb, Ab, WTx, WTa, qb, kb, vtb,
                                                        gqx, gkx, gqa, gka, ropetab);
  segG_kernel<<<dim3(512), dim3(256), 0, stream>>>(kb, vtb, G, zc);
  prefix_kernel<<<dim3(32,8), dim3(256), 0, stream>>>(G, zc, Mp, zpb);
  attn_mfma_kernel<<<dim3(512), dim3(256), 0, stream>>>(qb, kb, vtb, Mp, zpb, beta, out);
}

// Round 30
// 131.994 us; speedup vs baseline: 1.0780x; 1.0058x over previous
//
#include <hip/hip_runtime.h>

#define HEADS 16
#define DH    64
#define NA    2048
#define NX    2048
#define NTOT  4096
#define DIMK  1024
#define NQKV  3072
#define SEG   256
#define NSEG  16

typedef float          f32x4  __attribute__((ext_vector_type(4)));
typedef short          bf16x8 __attribute__((ext_vector_type(8)));
typedef unsigned int   u32x4  __attribute__((ext_vector_type(4)));

// f32 -> bf16 bits, round-to-nearest-even (finite inputs)
__device__ __forceinline__ unsigned short f2bf(float f){
  unsigned int u = __builtin_bit_cast(unsigned int, f);
  unsigned int r = 0x7fffu + ((u >> 16) & 1u);
  return (unsigned short)((u + r) >> 16);
}
__device__ __forceinline__ float bf2f(unsigned short u){
  return __builtin_bit_cast(float, ((unsigned int)u) << 16);
}
__device__ __forceinline__ unsigned pack2(float a, float b){
  return (unsigned)f2bf(a) | ((unsigned)f2bf(b) << 16);
}

__global__ __launch_bounds__(256) void zero_kernel(float* __restrict__ out, int n){
  int i = blockIdx.x * 256 + threadIdx.x;
  if (i < n) out[i] = 0.f;
}

// ---------------- K0: fused prep — cvt (x,a), wtr (wx,wa), rope table ----------------
// blocks [0,8192): cvt; [8192,14336): wtr; [14336,14848): rope table
__global__ __launch_bounds__(256) void prep_kernel(
    const float* __restrict__ x, const float* __restrict__ a,
    const float* __restrict__ Wx, const float* __restrict__ Wa,
    unsigned short* __restrict__ Xb, unsigned short* __restrict__ Ab,
    unsigned short* __restrict__ WTx, unsigned short* __restrict__ WTa,
    float* __restrict__ tab)
{
  __shared__ float tile[32][33];
  const int bid = blockIdx.x, tid = threadIdx.x;
  if (bid < 8192){
    const int i = bid * 256 + tid;                 // < 2097152
    const float* src = (i < 1048576) ? x : a;
    unsigned short* dst = (i < 1048576) ? Xb : Ab;
    const int j = i & 1048575;
    float4 v = ((const float4*)src)[j];
    ushort4 o;
    o.x = f2bf(v.x); o.y = f2bf(v.y); o.z = f2bf(v.z); o.w = f2bf(v.w);
    ((ushort4*)dst)[j] = o;
  } else if (bid < 14336){
    const int wid = bid - 8192;                    // < 6144
    const int z = wid / 3072, rem = wid - z*3072;
    const float* W = z ? Wa : Wx;
    unsigned short* WT = z ? WTa : WTx;
    const int c0 = (rem % 96) * 32, k0 = (rem / 96) * 32;
    const int tx = tid & 31, ty = tid >> 5;        // (32,8)
    #pragma unroll
    for (int i = 0; i < 32; i += 8) tile[ty+i][tx] = W[(size_t)(k0+ty+i)*NQKV + c0 + tx];
    __syncthreads();
    #pragma unroll
    for (int i = 0; i < 32; i += 8) WT[(size_t)(c0+ty+i)*DIMK + k0 + tx] = f2bf(tile[tx][ty+i]);
  } else {
    const int idx = (bid - 14336) * 256 + tid;     // < 131072
    const int n = idx >> 5, d = idx & 31;
    const float ang = (float)n * expf(-(float)d * 0.28782313662425572f);  // n * 10000^(-d/32)
    float sn, cs;
    sincosf(ang, &sn, &cs);
    float2 p; p.x = cs; p.y = sn;
    ((float2*)tab)[idx] = p;
  }
}

// ---------------- K1: bf16 MFMA GEMM: BK=64, 2-phase dbuf gload_lds + XCD chunk + 8mx6c supertile ----------------
// V-epilogue: LDS-transpose (reuse staging LDS post-loop) -> coalesced 16B stores (no 8KB-stride scatter).
__global__ __launch_bounds__(256,2) void gemm_qkv_kernel(
    const unsigned short* __restrict__ Xb, const unsigned short* __restrict__ Ab,
    const unsigned short* __restrict__ WTx, const unsigned short* __restrict__ WTa,
    unsigned short* __restrict__ qb, unsigned short* __restrict__ kb,
    unsigned short* __restrict__ vt,
    const float* __restrict__ gqx, const float* __restrict__ gkx,
    const float* __restrict__ gqa, const float* __restrict__ gka,
    const float* __restrict__ tab)
{
  __shared__ __align__(16) unsigned short As0[128*64];
  __shared__ __align__(16) unsigned short Bs0[128*64];
  __shared__ __align__(16) unsigned short As1[128*64];
  __shared__ __align__(16) unsigned short Bs1[128*64];

  // XCD chunking (bijective: 1536 % 8 == 0) + 8m x 6c supertiles (3.5 MB working set <= 4 MB L2/XCD)
  const int bid = blockIdx.x;                       // 0..1535
  const int lid = (bid & 7) * 192 + (bid >> 3);     // chunk-contiguous logical id
  const int strm = lid / 768;                       // 0 = x, 1 = a
  const int rem  = lid - strm * 768;
  const int cbase = (rem / 192) * 6;                // chunk's 6 c-panels
  const int idx   = rem % 192;
  const int st    = idx / 48;                       // 4 supertiles of 48 blocks
  const int si    = idx % 48;                       // 8m x 6c within supertile
  const int m0 = (st*8 + (si & 7)) * 128;
  const int c0 = (cbase + (si >> 3)) * 128;

  const unsigned short* Xp = strm ? Ab  : Xb;
  const unsigned short* Wp = strm ? WTa : WTx;
  const float* gq = strm ? gqa : gqx;
  const float* gk = strm ? gka : gkx;
  const int n_off = strm ? 0 : NA;

  const int tid  = threadIdx.x;
  const int lane = tid & 63, w = tid >> 6;
  const int wr = w >> 1, wc = w & 1;
  const int li = lane & 15, lg = lane >> 4;

  const int sr8  = lane >> 3;
  const int sch  = lane & 7;
  const int sswz = sch ^ sr8;
  const int rsw  = li & 7;

  f32x4 acc[4][4] = {};

  auto stage = [&](unsigned short* AsX, unsigned short* BsX, int kk){
    #pragma unroll
    for (int jj = 0; jj < 4; jj++){
      const int j = w*4 + jj;
      const int r = j*8 + sr8;
      __builtin_amdgcn_global_load_lds(
        (const __attribute__((address_space(1))) unsigned int*)(Xp + (size_t)(m0+r)*DIMK + kk + sswz*8),
        (__attribute__((address_space(3))) unsigned int*)(AsX + j*512), 16, 0, 0);
      __builtin_amdgcn_global_load_lds(
        (const __attribute__((address_space(1))) unsigned int*)(Wp + (size_t)(c0+r)*DIMK + kk + sswz*8),
        (__attribute__((address_space(3))) unsigned int*)(BsX + j*512), 16, 0, 0);
    }
  };
  auto compute = [&](const unsigned short* AsX, const unsigned short* BsX){
    #pragma unroll
    for (int kb2 = 0; kb2 < 2; kb2++){
      bf16x8 af[4], bf[4];
      const int slot = ((kb2*4 + lg) ^ rsw) * 8;
      #pragma unroll
      for (int m = 0; m < 4; m++)
        af[m] = *(const bf16x8*)(&AsX[(wr*64 + m*16 + li)*64 + slot]);
      #pragma unroll
      for (int n = 0; n < 4; n++)
        bf[n] = *(const bf16x8*)(&BsX[(wc*64 + n*16 + li)*64 + slot]);
      #pragma unroll
      for (int m = 0; m < 4; m++)
        #pragma unroll
        for (int n = 0; n < 4; n++)
          acc[m][n] = __builtin_amdgcn_mfma_f32_16x16x32_bf16(af[m], bf[n], acc[m][n], 0, 0, 0);
    }
  };

  stage(As0, Bs0, 0);
  __syncthreads();
  for (int t = 0; t < 16; t += 2){
    stage(As1, Bs1, (t+1)*64);
    compute(As0, Bs0);
    __syncthreads();
    if (t + 2 < 16) stage(As0, Bs0, (t+2)*64);
    compute(As1, Bs1);
    __syncthreads();
  }

  const int colbase = c0 + wc*64;           // one head per wave
  const int which = colbase >> 10;          // 0=q, 1=k, 2=v (wave-uniform)
  const int h = (colbase >> 6) & 15;

  if (which < 2){
    const float* gv = (which == 0) ? gq : gk;
    unsigned short* dstb = (which == 0) ? qb : kb;
    float gl[4];
    #pragma unroll
    for (int n = 0; n < 4; n++) gl[n] = gv[h*64 + n*16 + li];
    #pragma unroll
    for (int m = 0; m < 4; m++){
      #pragma unroll
      for (int r = 0; r < 4; r++){
        float ss = acc[m][0][r]*acc[m][0][r] + acc[m][1][r]*acc[m][1][r]
                 + acc[m][2][r]*acc[m][2][r] + acc[m][3][r]*acc[m][3][r];
        ss += __shfl_xor(ss, 1, 64);
        ss += __shfl_xor(ss, 2, 64);
        ss += __shfl_xor(ss, 4, 64);
        ss += __shfl_xor(ss, 8, 64);
        const float sc = 8.0f / fmaxf(sqrtf(ss), 1e-12f);
        float v0 = acc[m][0][r]*sc*gl[0], v1 = acc[m][1][r]*sc*gl[1];
        float v2 = acc[m][2][r]*sc*gl[2], v3 = acc[m][3][r]*sc*gl[3];
        const int row = m0 + wr*64 + m*16 + lg*4 + r;
        const int bb = row >> 11, nn = row & 2047;
        const int n_g = nn + n_off;
        const float2 cs0 = ((const float2*)tab)[n_g*32 + li];        // fd = li
        const float2 cs1 = ((const float2*)tab)[n_g*32 + 16 + li];   // fd = 16+li
        const float o0 = v0*cs0.x - v2*cs0.y;   // d = li
        const float o1 = v1*cs1.x - v3*cs1.y;   // d = 16+li
        const float o2 = v2*cs0.x + v0*cs0.y;   // d = 32+li
        const float o3 = v3*cs1.x + v1*cs1.y;   // d = 48+li
        unsigned short* drow = dstb + ((size_t)(bb*HEADS + h)*NTOT + (size_t)n_g)*64;
        drow[li]      = f2bf(o0);
        drow[16 + li] = f2bf(o1);
        drow[32 + li] = f2bf(o2);
        drow[48 + li] = f2bf(o3);
      }
    }
  } else {
    // V: transpose via wave-private LDS scratch (staging LDS is dead after final barrier),
    // then fully-coalesced 16B stores of contiguous vt rows.
    // scratch layout: [d_local][64] stride 64, 8-elem chunk XOR'd by (d_local&7) on both sides.
    unsigned short* scratch = ((w < 2) ? As0 : As1) + (w & 1) * 4096;   // 64x64 bf16 = 8KB
    #pragma unroll
    for (int m = 0; m < 4; m++){
      #pragma unroll
      for (int n = 0; n < 4; n++){
        // rows m*16+lg*4+{0..3} of this wave's tile, col d_local = n*16+li
        const int dl = n*16 + li;
        const int cchunk = (m*2 + (lg >> 1)) ^ (li & 7);   // (row_local/8) ^ (d_local&7)
        uint2 pw;
        pw.x = pack2(acc[m][n][0], acc[m][n][1]);
        pw.y = pack2(acc[m][n][2], acc[m][n][3]);
        *(uint2*)(scratch + dl*64 + cchunk*8 + (lg & 1)*4) = pw;
      }
    }
    const int row0 = m0 + wr*64;
    const int bb = row0 >> 11;
    const int n_g0 = (row0 & 2047) + n_off;
    unsigned short* vb = vt + (size_t)(bb*HEADS + h)*DH*NTOT;
    #pragma unroll
    for (int it2 = 0; it2 < 8; it2++){
      const int chunkid = lane + it2*64;     // 0..511
      const int d = chunkid >> 3;            // d_local 0..63
      const int c8 = chunkid & 7;
      u32x4 val = *(const u32x4*)(scratch + d*64 + ((c8 ^ (d & 7)) * 8));
      *(u32x4*)(vb + (size_t)d*NTOT + n_g0 + c8*8) = val;
    }
  }
}

// ---------------- K3: MFMA segG: G = skT (64x256) x v (256x64), zc = row-sum(skT) ----------------
__global__ __launch_bounds__(256,2) void segG_kernel(const unsigned short* __restrict__ kb,
                                                     const unsigned short* __restrict__ vt,
                                                     float* __restrict__ G, float* __restrict__ zc){
  __shared__ unsigned short skT[64*264];   // [d][l], stride 264
  __shared__ unsigned short Vts[64*264];   // [e][l], stride 264
  const int blk = blockIdx.x;              // bh*16 + s
  const int bh = blk >> 4, s = blk & 15;
  const int tid = threadIdx.x;
  const int w = tid >> 6, lane = tid & 63;
  const int li = lane & 15, lg = lane >> 4;
  const size_t segoffb = ((size_t)bh * NTOT + (size_t)s * SEG) * DH;

  #pragma unroll
  for (int it = 0; it < 8; it++){
    const int idx = tid + it*256;          // 2048 b128 chunks
    const int e = idx >> 5, jc = idx & 31;
    *(u32x4*)(Vts + e*264 + jc*8) =
      *(const u32x4*)(vt + (size_t)bh*DH*NTOT + (size_t)e*NTOT + s*SEG + jc*8);
  }
  // skT = elu(k)+1 transposed; k already bf16
  #pragma unroll
  for (int it = 0; it < 8; it++){
    const int idx = tid + it*256;          // 2048 chunks of 8 dims
    const int l = idx >> 3, dc = idx & 7;
    bf16x8 kk = *(const bf16x8*)(kb + segoffb + (size_t)l*64 + dc*8);
    #pragma unroll
    for (int t2 = 0; t2 < 8; t2++){
      const float xx = bf2f((unsigned short)kk[t2]);
      skT[(dc*8 + t2)*264 + l] = f2bf(xx > 0.f ? xx + 1.f : __expf(xx));
    }
  }
  __syncthreads();

  // zc: 4 threads per d-row
  {
    const int d = tid >> 2, q = tid & 3;
    float zz = 0.f;
    #pragma unroll
    for (int u = 0; u < 8; u++){
      bf16x8 vv = *(const bf16x8*)(skT + d*264 + q*64 + u*8);
      #pragma unroll
      for (int t2 = 0; t2 < 8; t2++)
        zz += bf2f((unsigned short)vv[t2]);
    }
    zz += __shfl_xor(zz, 1, 64);
    zz += __shfl_xor(zz, 2, 64);
    if (q == 0) zc[(size_t)blk*64 + d] = zz;
  }

  f32x4 acc[4] = {};
  #pragma unroll
  for (int k0 = 0; k0 < 256; k0 += 32){
    bf16x8 af = *(const bf16x8*)(skT + (w*16 + li)*264 + k0 + lg*8);
    #pragma unroll
    for (int n = 0; n < 4; n++){
      bf16x8 bf = *(const bf16x8*)(Vts + (n*16 + li)*264 + k0 + lg*8);
      acc[n] = __builtin_amdgcn_mfma_f32_16x16x32_bf16(af, bf, acc[n], 0, 0, 0);
    }
  }
  float* Gout = G + (size_t)blk * DH * DH;
  #pragma unroll
  for (int n = 0; n < 4; n++)
    #pragma unroll
    for (int r = 0; r < 4; r++)
      Gout[(w*16 + lg*4 + r)*64 + n*16 + li] = acc[n][r];
}

// ---------------- K4: exclusive prefix over segments -> Mp, zp (parallelized: grid 32x8) ----------------
__global__ __launch_bounds__(256) void prefix_kernel(const float* __restrict__ G,
                                                     const float* __restrict__ zc,
                                                     float* __restrict__ Mp, float* __restrict__ zp){
  const int bh = blockIdx.x, c = blockIdx.y, tid = threadIdx.x;
  const int e = c*512 + tid;          // this block handles elems [c*512, c*512+512)
  float run0 = 0.f, run1 = 0.f;
  for (int s = 0; s < NSEG; s++){
    const size_t base = ((size_t)bh * NSEG + s) * 4096;
    Mp[base + e]       = run0;  run0 += G[base + e];
    Mp[base + e + 256] = run1;  run1 += G[base + e + 256];
  }
  if (c == 0 && tid < DH){
    float rz = 0.f;
    for (int s = 0; s < NSEG; s++){
      zp[((size_t)bh*NSEG + s)*DH + tid] = rz;
      rz += zc[((size_t)bh*NSEG + s)*DH + tid];
    }
  }
}

// ---------------- K5: MFMA flash-attention; Q in registers, SQ in-register (no Qs/den_s LDS) ----------------
__global__ __launch_bounds__(256,1) void attn_mfma_kernel(
    const unsigned short* __restrict__ qb, const unsigned short* __restrict__ kb,
    const unsigned short* __restrict__ vt, const float* __restrict__ Mp,
    const float* __restrict__ zp, const float* __restrict__ beta,
    float* __restrict__ out)
{
  __shared__ unsigned short KSs[256*72];   // K [row][d], stride 72
  __shared__ unsigned short Vts[64*264];   // [e][j], stride 264
  __shared__ unsigned short Ps[4*64*72];   // per-wave P [i][j]
  __shared__ unsigned short Mts[64*72];    // M^T [e][d]
  __shared__ float zsh[64];

  const int blk = blockIdx.x;
  const int s = blk & 15, bh = blk >> 4;
  const int h = bh & 15, b = bh >> 4;
  const int tid = threadIdx.x;
  const int w = tid >> 6, lane = tid & 63;
  const int li = lane & 15, lg = lane >> 4;
  const size_t segoffb = ((size_t)bh * NTOT + (size_t)s * SEG) * DH;

  // K staging (rows are 128B contiguous)
  #pragma unroll
  for (int it = 0; it < 8; it++){
    const int idx = tid + it*256;            // 2048 chunks of 16B
    const int row = idx >> 3, jc = idx & 7;
    *(u32x4*)(KSs + row*72 + jc*8) = *(const u32x4*)(kb + segoffb + (size_t)row*64 + jc*8);
  }
  #pragma unroll
  for (int it = 0; it < 8; it++){
    const int idx = tid + it*256;            // 2048 b128 chunks
    const int e = idx >> 5, jc = idx & 31;
    *(u32x4*)(Vts + e*264 + jc*8) =
      *(const u32x4*)(vt + (size_t)bh*DH*NTOT + (size_t)e*NTOT + s*SEG + jc*8);
  }
  #pragma unroll
  for (int it = 0; it < 16; it++){
    const int idx = tid + it*256;            // 4096 elems of Mp [d][e]
    const int d = idx >> 6, e = idx & 63;
    Mts[e*72 + d] = f2bf(Mp[(size_t)blk*4096 + d*64 + e]);
  }
  if (tid < 64) zsh[tid] = zp[(size_t)blk*64 + tid];

  // Q fragments direct from global (wave's own 64 rows)
  const int qrow0 = w*64;
  bf16x8 qf[4][2];
  #pragma unroll
  for (int it = 0; it < 4; it++)
    #pragma unroll
    for (int kb2 = 0; kb2 < 2; kb2++)
      qf[it][kb2] = *(const bf16x8*)(qb + segoffb + (size_t)(qrow0 + it*16 + li)*64 + kb2*32 + lg*8);
  __syncthreads();

  f32x4 o_acc[4][4] = {};
  float denr[4] = {0.f, 0.f, 0.f, 0.f};

  for (int c = 0; c <= w; c++){
    f32x4 st[4][4] = {};
    #pragma unroll
    for (int jt = 0; jt < 4; jt++){
      bf16x8 kf0 = *(const bf16x8*)(KSs + (c*64 + jt*16 + li)*72 + 0  + lg*8);
      bf16x8 kf1 = *(const bf16x8*)(KSs + (c*64 + jt*16 + li)*72 + 32 + lg*8);
      #pragma unroll
      for (int it = 0; it < 4; it++){
        st[jt][it] = __builtin_amdgcn_mfma_f32_16x16x32_bf16(kf0, qf[it][0], st[jt][it], 0, 0, 0);
        st[jt][it] = __builtin_amdgcn_mfma_f32_16x16x32_bf16(kf1, qf[it][1], st[jt][it], 0, 0, 0);
      }
    }
    const bool diag = (c == w);
    #pragma unroll
    for (int jt = 0; jt < 4; jt++){
      #pragma unroll
      for (int it = 0; it < 4; it++){
        f32x4 p = st[jt][it];
        unsigned pb[4];
        #pragma unroll
        for (int r = 0; r < 4; r++){
          float pe = __expf(p[r] * 0.125f);
          if (diag && (jt*16 + lg*4 + r > it*16 + li)) pe = 0.f;
          pb[r] = __builtin_bit_cast(unsigned, pe) & 0xFFFF0000u;   // bf16 truncation
          p[r] = __builtin_bit_cast(float, pb[r]);                  // value actually used in PV
        }
        denr[it] += (p[0] + p[1]) + (p[2] + p[3]);
        uint2 pkk;
        pkk.x = (pb[0] >> 16) | pb[1];
        pkk.y = (pb[2] >> 16) | pb[3];
        *(uint2*)(Ps + w*4608 + (it*16 + li)*72 + jt*16 + lg*4) = pkk;
      }
    }
    bf16x8 pf[4][2];
    #pragma unroll
    for (int it = 0; it < 4; it++)
      #pragma unroll
      for (int kb2 = 0; kb2 < 2; kb2++)
        pf[it][kb2] = *(const bf16x8*)(Ps + w*4608 + (it*16 + li)*72 + kb2*32 + lg*8);
    #pragma unroll
    for (int et = 0; et < 4; et++){
      bf16x8 vf0 = *(const bf16x8*)(Vts + (et*16 + li)*264 + c*64 + 0  + lg*8);
      bf16x8 vf1 = *(const bf16x8*)(Vts + (et*16 + li)*264 + c*64 + 32 + lg*8);
      #pragma unroll
      for (int it = 0; it < 4; it++){
        o_acc[it][et] = __builtin_amdgcn_mfma_f32_16x16x32_bf16(pf[it][0], vf0, o_acc[it][et], 0, 0, 0);
        o_acc[it][et] = __builtin_amdgcn_mfma_f32_16x16x32_bf16(pf[it][1], vf1, o_acc[it][et], 0, 0, 0);
      }
    }
  }

  // softmax denominator: full reduction across lg groups
  #pragma unroll
  for (int it = 0; it < 4; it++){
    denr[it] += __shfl_xor(denr[it], 16, 64);
    denr[it] += __shfl_xor(denr[it], 32, 64);
  }
  const float gate = 1.f / (1.f + __expf(-beta[h]));

  // in-register SQ (A-frag layout) + per-row denm via shfl reduce
  bf16x8 sqf[4][2];
  #pragma unroll
  for (int it = 0; it < 4; it++){
    float sqv[16];
    float denm = 0.f;
    #pragma unroll
    for (int kb2 = 0; kb2 < 2; kb2++){
      #pragma unroll
      for (int t2 = 0; t2 < 8; t2++){
        const float xq = bf2f((unsigned short)qf[it][kb2][t2]);
        const float sq = xq > 0.f ? xq + 1.f : __expf(xq);
        sqv[kb2*8 + t2] = sq;
        denm += sq * zsh[kb2*32 + lg*8 + t2];
      }
    }
    denm += __shfl_xor(denm, 16, 64);
    denm += __shfl_xor(denm, 32, 64);
    const float c2 = gate / (denm + 1e-6f);
    #pragma unroll
    for (int kb2 = 0; kb2 < 2; kb2++){
      union { bf16x8 v; unsigned u[4]; } cc;
      #pragma unroll
      for (int p2 = 0; p2 < 4; p2++)
        cc.u[p2] = pack2(sqv[kb2*8 + 2*p2] * c2, sqv[kb2*8 + 2*p2 + 1] * c2);
      sqf[it][kb2] = cc.v;
    }
  }

  // scale local term by (1-gate)/den (den broadcast via shfl from lane lg*4+r)
  #pragma unroll
  for (int it = 0; it < 4; it++){
    #pragma unroll
    for (int r = 0; r < 4; r++){
      const float c1 = (1.f - gate) / __shfl(denr[it], lg*4 + r, 64);
      #pragma unroll
      for (int et = 0; et < 4; et++) o_acc[it][et][r] *= c1;
    }
  }
  // memory term MFMA with in-register sqf
  #pragma unroll
  for (int kb2 = 0; kb2 < 2; kb2++){
    bf16x8 mf[4];
    #pragma unroll
    for (int et = 0; et < 4; et++)
      mf[et] = *(const bf16x8*)(Mts + (et*16 + li)*72 + kb2*32 + lg*8);
    #pragma unroll
    for (int it = 0; it < 4; it++){
      #pragma unroll
      for (int et = 0; et < 4; et++)
        o_acc[it][et] = __builtin_amdgcn_mfma_f32_16x16x32_bf16(sqf[it][kb2], mf[et], o_acc[it][et], 0, 0, 0);
    }
  }

  #pragma unroll
  for (int it = 0; it < 4; it++){
    #pragma unroll
    for (int r = 0; r < 4; r++){
      const int n_g = s*SEG + qrow0 + it*16 + lg*4 + r;
      size_t o;
      if (n_g >= NA) o = ((size_t)b * NX + (size_t)(n_g - NA)) * 1024 + h * 64;
      else           o = 4194304u + ((size_t)b * NA + (size_t)n_g) * 1024 + h * 64;
      #pragma unroll
      for (int et = 0; et < 4; et++)
        out[o + et*16 + li] = o_acc[it][et][r];
    }
  }
}

extern "C" void kernel_launch(void* const* d_in, const int* in_sizes, int n_in,
                              void* d_out, int out_size, void* d_ws, size_t ws_size,
                              hipStream_t stream)
{
  (void)ws_size;
  const int expect[9] = {4194304, 4194304, 3145728, 3145728, 1024, 1024, 1024, 1024, 16};
  bool ok = (n_in == 9);
  if (ok) for (int i = 0; i < 9; i++) if (in_sizes[i] != expect[i]) { ok = false; break; }
  float* out = (float*)d_out;
  if (!ok){
    zero_kernel<<<dim3((out_size + 255)/256), dim3(256), 0, stream>>>(out, out_size);
    return;
  }

  const float* x    = (const float*)d_in[0];
  const float* a    = (const float*)d_in[1];
  const float* wx   = (const float*)d_in[2];
  const float* wa   = (const float*)d_in[3];
  const float* gqx  = (const float*)d_in[4];
  const float* gkx  = (const float*)d_in[5];
  const float* gqa  = (const float*)d_in[6];
  const float* gka  = (const float*)d_in[7];
  const float* beta = (const float*)d_in[8];

  // Workspace layout (~97.8 MB)
  char* wsb = (char*)d_ws;
  unsigned short* qb  = (unsigned short*)wsb;     // 16,777,216 B  [bh][n][d] bf16
  unsigned short* kb  = qb + 8388608;             // 16,777,216 B
  unsigned short* vtb = kb + 8388608;             // 16,777,216 B  [bh][d][n] bf16
  unsigned short* Xb  = vtb + 8388608;            //  8,388,608 B
  unsigned short* Ab  = Xb + 4194304;             //  8,388,608 B
  unsigned short* WTx = Ab + 4194304;             //  6,291,456 B
  unsigned short* WTa = WTx + 3145728;            //  6,291,456 B
  float* ropetab = (float*)(WTa + 3145728);       //  1,048,576 B
  float* G   = ropetab + 262144;                  //  8,388,608 B
  float* Mp  = G + 2097152;                       //  8,388,608 B
  float* zc  = Mp + 2097152;                      //    131,072 B
  float* zpb = zc + 32768;                        //    131,072 B

  prep_kernel<<<dim3(14848), dim3(256), 0, stream>>>(x, a, wx, wa, Xb, Ab, WTx, WTa, ropetab);
  // a tokens occupy concatenated positions [0,2048); x tokens [2048,4096)
  gemm_qkv_kernel<<<dim3(1536), dim3(256), 0, stream>>>(Xb, Ab, WTx, WTa, qb, kb, vtb,
                                                        gqx, gkx, gqa, gka, ropetab);
  segG_kernel<<<dim3(512), dim3(256), 0, stream>>>(kb, vtb, G, zc);
  prefix_kernel<<<dim3(32,8), dim3(256), 0, stream>>>(G, zc, Mp, zpb);
  attn_mfma_kernel<<<dim3(512), dim3(256), 0, stream>>>(qb, kb, vtb, Mp, zpb, beta, out);
}